// Round 5
// baseline (1365.712 us; speedup 1.0000x reference)
//
#include <hip/hip_runtime.h>

#define LTOT 2048
#define BATCH 2
#define NTOK 4096
#define DMODEL 2048
#define DSTATE 128
#define NH 64
#define HD 64
#define DINNER 4096
#define CONVD 4352
#define XDTC 4416
#define INP 8512
#define INTER_ 5632
#define CHUNK_ 128
#define NCH 16
#define EPSF 1e-6f

typedef __bf16 bf16x8 __attribute__((ext_vector_type(8)));
typedef float f32x4 __attribute__((ext_vector_type(4)));
typedef unsigned short u16x4 __attribute__((ext_vector_type(4)));
typedef unsigned short u16x8 __attribute__((ext_vector_type(8)));

__device__ __forceinline__ unsigned short f2b(float f){
  unsigned int u = __builtin_bit_cast(unsigned int, f);
  u += 0x7fffu + ((u >> 16) & 1u);
  return (unsigned short)(u >> 16);
}
__device__ __forceinline__ float b2f(unsigned short h){
  return __builtin_bit_cast(float, ((unsigned int)h) << 16);
}
__device__ __forceinline__ f32x4 mfma16(bf16x8 a, bf16x8 b, f32x4 c){
  return __builtin_amdgcn_mfma_f32_16x16x32_bf16(a, b, c, 0, 0, 0);
}
// async global->LDS, 16B per lane, wave-uniform LDS base + lane*16
typedef const __attribute__((address_space(1))) void* gas_t;
typedef __attribute__((address_space(3))) void* las_t;
__device__ __forceinline__ void gload16(const void* g, void* l){
  __builtin_amdgcn_global_load_lds((gas_t)g, (las_t)l, 16, 0, 0);
}

// ---------------- weight convert: fp32 W[K][N] -> bf16 WT[Npad][K], zero rows n>=N ----------------
__global__ __launch_bounds__(256) void wconv_kernel(const float* __restrict__ W,
                                                    unsigned short* __restrict__ WT,
                                                    int K, int N)
{
  __shared__ unsigned short t[64][72];
  int n0 = blockIdx.x * 64, k0 = blockIdx.y * 64;
  int tid = threadIdx.x;
  int kl = tid >> 4, nl4 = (tid & 15) * 4;
  #pragma unroll
  for (int it = 0; it < 4; it++){
    int kk = kl + it * 16;
    float4 v = make_float4(0.f, 0.f, 0.f, 0.f);
    if (n0 < N) v = *(const float4*)&W[(size_t)(k0 + kk) * N + n0 + nl4];
    t[nl4 + 0][kk] = f2b(v.x);
    t[nl4 + 1][kk] = f2b(v.y);
    t[nl4 + 2][kk] = f2b(v.z);
    t[nl4 + 3][kk] = f2b(v.w);
  }
  __syncthreads();
  int nr = tid >> 3, k8 = (tid & 7) * 8;
  #pragma unroll
  for (int it = 0; it < 2; it++){
    int nn = nr + it * 32;
    *(u16x8*)&WT[(size_t)(n0 + nn) * K + k0 + k8] = *(const u16x8*)&t[nn][k8];
  }
}

// ---------------- RMSNorm: fp32 in -> bf16 out ----------------
__global__ __launch_bounds__(256) void rms_kernel(const float* __restrict__ x,
                                                  const float* __restrict__ w,
                                                  unsigned short* __restrict__ out, int width)
{
  int row = blockIdx.x, tid = threadIdx.x;
  const float* xr = x + (size_t)row * width;
  unsigned short* orow = out + (size_t)row * width;
  int nv = width >> 2;
  float ss = 0.f;
  for (int i = tid; i < nv; i += 256){
    float4 v = ((const float4*)xr)[i];
    ss += v.x*v.x + v.y*v.y + v.z*v.z + v.w*v.w;
  }
  #pragma unroll
  for (int off = 32; off > 0; off >>= 1) ss += __shfl_down(ss, off, 64);
  __shared__ float red[4];
  if ((tid & 63) == 0) red[tid >> 6] = ss;
  __syncthreads();
  float tot = red[0] + red[1] + red[2] + red[3];
  float scale = rsqrtf(tot / (float)width + EPSF);
  for (int i = tid; i < nv; i += 256){
    float4 v = ((const float4*)xr)[i];
    float4 wv = ((const float4*)w)[i];
    u16x4 o = { f2b(v.x * scale * wv.x), f2b(v.y * scale * wv.y),
                f2b(v.z * scale * wv.z), f2b(v.w * scale * wv.w) };
    ((u16x4*)orow)[i] = o;
  }
}

// ---------------- Gated RMSNorm: y fp32, z bf16 -> out bf16 ----------------
__global__ __launch_bounds__(256) void rms_gated_kernel(const float* __restrict__ y,
                                                        const unsigned short* __restrict__ z,
                                                        const float* __restrict__ w,
                                                        unsigned short* __restrict__ out)
{
  int row = blockIdx.x, tid = threadIdx.x;
  const float* yr = y + (size_t)row * DINNER;
  const unsigned short* zr = z + (size_t)row * DINNER;
  unsigned short* orow = out + (size_t)row * DINNER;
  float g[16];
  float ss = 0.f;
  #pragma unroll
  for (int ii = 0; ii < 4; ii++){
    int i = tid + ii * 256;
    float4 yv = ((const float4*)yr)[i];
    u16x4 zv = ((const u16x4*)zr)[i];
    #pragma unroll
    for (int e = 0; e < 4; e++){
      float zf = b2f(zv[e]);
      float yf = (&yv.x)[e];
      float gg = yf * (zf / (1.f + expf(-zf)));
      g[ii * 4 + e] = gg;
      ss += gg * gg;
    }
  }
  #pragma unroll
  for (int off = 32; off > 0; off >>= 1) ss += __shfl_down(ss, off, 64);
  __shared__ float red[4];
  if ((tid & 63) == 0) red[tid >> 6] = ss;
  __syncthreads();
  float tot = red[0] + red[1] + red[2] + red[3];
  float scale = rsqrtf(tot / (float)DINNER + EPSF);
  #pragma unroll
  for (int ii = 0; ii < 4; ii++){
    int i = tid + ii * 256;
    float4 wv = ((const float4*)w)[i];
    u16x4 o;
    #pragma unroll
    for (int e = 0; e < 4; e++) o[e] = f2b(g[ii * 4 + e] * scale * (&wv.x)[e]);
    ((u16x4*)orow)[i] = o;
  }
}

// ---------------- GEMM2: 256x256 tile, BK=64, 8 waves, 4-phase pipelined schedule ----------------
// C = A(bf16,[M][K]) * BT(bf16,[Npad][K])^T. Dynamic LDS 128KB: 2 bufs x (A 32KB + B 32KB).
// Invariant: at tile t start, buf[t&1] complete; tile t+1 staged into buf[(t+1)&1] during
// phases 0-1 of tile t (that buffer's last reader passed a barrier in tile t-1).
// k-XOR swizzle (zero bank conflicts, verified R4); XCD-aware bijective block swizzle.
__global__ __launch_bounds__(512, 1) void gemm2_kernel(const unsigned short* __restrict__ A,
                                                       const unsigned short* __restrict__ BT,
                                                       const float* __restrict__ addsrc,
                                                       float* __restrict__ Cf,
                                                       unsigned short* __restrict__ Cb,
                                                       unsigned short* __restrict__ Cb2, int splitN,
                                                       const unsigned short* __restrict__ gate,
                                                       float* __restrict__ dtraw,
                                                       int M, int N, int K)
{
  extern __shared__ unsigned short lds[];    // 65536 u16 = 128 KB
  int tid = threadIdx.x, lane = tid & 63, w = tid >> 6;
  int wm = w >> 2, wn = w & 3;               // wave grid 2(M) x 4(N); wave block 128x64
  int bid = blockIdx.x + blockIdx.y * gridDim.x;
  int nwg = gridDim.x * gridDim.y;
  int q8 = nwg >> 3, r8 = nwg & 7;
  int xcd = bid & 7, boff = bid >> 3;
  int wgid = (xcd < r8 ? xcd * (q8 + 1) : r8 * (q8 + 1) + (xcd - r8) * q8) + boff;
  int bn = (wgid % gridDim.x) * 256;
  int bm = (wgid / gridDim.x) * 256;

  int srow = lane >> 3;                      // row within 8-row wave-stripe
  int sk   = ((lane & 7) ^ srow) << 3;       // pre-swizzled source k-offset
  int kswz = (lane & 7) << 3;                // read-side XOR

  f32x4 acc[8][4] = {};
  int NT = K >> 6;

  // prologue: stage tile 0 -> buf0 (8 gloads/thread: 4 A-chunks + 4 B-chunks of 64 rows)
  #pragma unroll
  for (int co = 0; co < 4; ++co){
    int row = co * 64 + w * 8 + srow;
    gload16(&A [(size_t)(bm + row) * K + sk],          &lds[co * 4096 + w * 512]);
    gload16(&BT[(size_t)(bn + row) * K + sk],          &lds[16384 + co * 4096 + w * 512]);
  }
  asm volatile("s_waitcnt vmcnt(0)" ::: "memory");
  __builtin_amdgcn_s_barrier();
  asm volatile("" ::: "memory");

  for (int t = 0; t < NT; ++t){
    int cur = t & 1;
    unsigned short* Asc = &lds[cur * 32768];
    unsigned short* Bsc = &lds[cur * 32768 + 16384];
    unsigned short* Asn = &lds[(cur ^ 1) * 32768];
    unsigned short* Bsn = &lds[(cur ^ 1) * 32768 + 16384];
    size_t k0n = (size_t)(t + 1) << 6;
    bool pf = (t + 1 < NT);
    bf16x8 bfr[2][4];
    #pragma unroll
    for (int q = 0; q < 4; ++q){
      // issue next-tile prefetch: 4 gloads in phase 0, 4 in phase 1
      if (q < 2 && pf){
        #pragma unroll
        for (int h = 0; h < 2; ++h){
          int co = q * 2 + h;
          int row = co * 64 + w * 8 + srow;
          gload16(&A [(size_t)(bm + row) * K + k0n + sk], &Asn[co * 4096 + w * 512]);
          gload16(&BT[(size_t)(bn + row) * K + k0n + sk], &Bsn[co * 4096 + w * 512]);
        }
      }
      // B fragments: read once per tile (phase 0), held in regs — halves LDS traffic
      if (q == 0){
        #pragma unroll
        for (int kk2 = 0; kk2 < 2; ++kk2){
          int kcol = (kk2 * 32 + (lane >> 4) * 8) ^ kswz;
          #pragma unroll
          for (int c = 0; c < 4; ++c)
            bfr[kk2][c] = *(const bf16x8*)&Bsc[(wn * 64 + c * 16 + (lane & 15)) * 64 + kcol];
        }
      }
      // A fragments for this phase (rows q*32 .. q*32+31 of the wave's 128)
      bf16x8 afr[2][2];
      #pragma unroll
      for (int kk2 = 0; kk2 < 2; ++kk2){
        int kcol = (kk2 * 32 + (lane >> 4) * 8) ^ kswz;
        #pragma unroll
        for (int r = 0; r < 2; ++r)
          afr[kk2][r] = *(const bf16x8*)&Asc[(wm * 128 + q * 32 + r * 16 + (lane & 15)) * 64 + kcol];
      }
      asm volatile("" ::: "memory");
      __builtin_amdgcn_s_barrier();          // rendezvous: align MFMA clusters across waves
      __builtin_amdgcn_s_setprio(1);
      #pragma unroll
      for (int kk2 = 0; kk2 < 2; ++kk2)
        #pragma unroll
        for (int r = 0; r < 2; ++r)
          #pragma unroll
          for (int c = 0; c < 4; ++c)
            acc[q * 2 + r][c] = mfma16(afr[kk2][r], bfr[kk2][c], acc[q * 2 + r][c]);
      __builtin_amdgcn_s_setprio(0);
      if (q == 3)
        asm volatile("s_waitcnt vmcnt(0) lgkmcnt(0)" ::: "memory");  // tile t+1 landed; reads retired
      else
        asm volatile("" ::: "memory");
      __builtin_amdgcn_s_barrier();
      asm volatile("" ::: "memory");
    }
  }

  // epilogue (no LDS use)
  int r0 = bm + wm * 128 + ((lane >> 4) << 2);
  int c0 = bn + wn * 64 + (lane & 15);
  #pragma unroll
  for (int i = 0; i < 8; ++i){
    #pragma unroll
    for (int j = 0; j < 4; ++j){
      int cc = c0 + j * 16;
      if (cc < N){
        #pragma unroll
        for (int e = 0; e < 4; ++e){
          int rr = r0 + i * 16 + e;
          float v = acc[i][j][e];
          if (Cf){
            size_t idx = (size_t)rr * N + cc;
            if (addsrc) v += addsrc[idx];
            Cf[idx] = v;
          } else if (cc < splitN){
            size_t idx = (size_t)rr * splitN + cc;
            float vv = v;
            if (gate){ float gg = b2f(gate[idx]); vv = gg / (1.f + expf(-gg)) * v; }
            Cb[idx] = f2b(vv);
          } else {
            Cb2[(size_t)rr * (N - splitN) + (cc - splitN)] = f2b(v);
            if (dtraw && cc >= N - NH) dtraw[(size_t)rr * NH + (cc - (N - NH))] = v;
          }
        }
      }
    }
  }
}

// ---------------- dt = softplus(dtraw + dt_bias), fp32 path ----------------
__global__ __launch_bounds__(256) void dt_kernel(const float* __restrict__ dtraw,
                                                 const float* __restrict__ dt_bias,
                                                 float* __restrict__ dtb)
{
  int idx = blockIdx.x * 256 + threadIdx.x;
  float raw = dtraw[idx] + dt_bias[idx & 63];
  dtb[idx] = (raw > 20.f) ? raw : log1pf(expf(raw));
}

// ---------------- per (b,h,c) inclusive cumsum of dA = dt*A within chunk ----------------
__global__ __launch_bounds__(64) void acum_kernel(const float* __restrict__ dtb,
                                                  const float* __restrict__ A_log,
                                                  float* __restrict__ acum)
{
  int bid = blockIdx.x;          // (b*NH + h)*NCH + c
  int c = bid & 15;
  int hh = (bid >> 4) & 63;
  int b = bid >> 10;
  int lane = threadIdx.x;
  float Av = -expf(A_log[hh]);
  int rowbase = b * LTOT + c * CHUNK_;
  float v0 = dtb[(size_t)(rowbase + 2 * lane) * NH + hh] * Av;
  float v1 = dtb[(size_t)(rowbase + 2 * lane + 1) * NH + hh] * Av;
  float s = v0 + v1;
  #pragma unroll
  for (int d = 1; d < 64; d <<= 1){
    float t = __shfl_up(s, d, 64);
    if (lane >= d) s += t;
  }
  float excl = s - (v0 + v1);
  float* dst = acum + ((size_t)(b * NH + hh)) * LTOT + c * CHUNK_;
  dst[2 * lane]     = excl + v0;
  dst[2 * lane + 1] = excl + v0 + v1;
}

// ---------------- depthwise causal conv (width 4) + bias + SiLU, bf16 in/out ----------------
__global__ __launch_bounds__(256) void conv_kernel(const unsigned short* __restrict__ xdt,
                                                   const float* __restrict__ cw,
                                                   const float* __restrict__ cb,
                                                   unsigned short* __restrict__ xbc)
{
  int ch = blockIdx.x * 256 + threadIdx.x;   // 17*256 = 4352 = CONVD exactly
  int l = blockIdx.y, b = blockIdx.z;
  float acc = cb[ch];
  #pragma unroll
  for (int j = 0; j < 4; j++){
    int ls = l + j - 3;
    if (ls >= 0) acc += b2f(xdt[((size_t)(b * LTOT + ls)) * XDTC + ch]) * cw[ch * 4 + j];
  }
  acc = acc / (1.f + expf(-acc));
  xbc[((size_t)(b * LTOT + l)) * CONVD + ch] = f2b(acc);
}

// ---------------- SSD part 1: S' = (C·B^T)⊙L, Y_diag = S'·(x·dt)^T ----------------
__global__ __launch_bounds__(256) void ssd_sy_kernel(const unsigned short* __restrict__ xbc,
                                                     const float* __restrict__ dtb,
                                                     const float* __restrict__ acum,
                                                     float* __restrict__ y)
{
  int hh = blockIdx.x;
  int c = blockIdx.y >> 1;
  int half = blockIdx.y & 1;
  int b = blockIdx.z;
  __shared__ unsigned short Cs[64][136];    // C rows (l0..l0+63), later S'
  __shared__ unsigned short Bs[128][136];   // B rows (all s), later XT (rows 0..63 = p)
  __shared__ float ac[128];
  int tid = threadIdx.x, lane = tid & 63, w = tid >> 6;
  int l0 = half * 64;
  size_t rowbase = (size_t)b * LTOT + c * CHUNK_;
  if (tid < 128) ac[tid] = acum[((size_t)(b * NH + hh)) * LTOT + c * CHUNK_ + tid];
  #pragma unroll
  for (int p = 0; p < 8; p++){
    int lr = p * 8 + (tid >> 5);
    int n4 = (tid & 31) * 4;
    *(u16x4*)&Cs[lr][n4] =
      *(const u16x4*)&xbc[(rowbase + l0 + lr) * CONVD + DINNER + DSTATE + n4];
  }
  #pragma unroll
  for (int p = 0; p < 16; p++){
    int s = p * 8 + (tid >> 5);
    int n4 = (tid & 31) * 4;
    *(u16x4*)&Bs[s][n4] = *(const u16x4*)&xbc[(rowbase + s) * CONVD + DINNER + n4];
  }
  __syncthreads();
  f32x4 accS[8] = {};
  #pragma unroll
  for (int kk = 0; kk < 4; kk++){
    bf16x8 a = *(const bf16x8*)&Cs[w * 16 + (lane & 15)][kk * 32 + (lane >> 4) * 8];
    #pragma unroll
    for (int fc = 0; fc < 8; fc++){
      bf16x8 bb = *(const bf16x8*)&Bs[fc * 16 + (lane & 15)][kk * 32 + (lane >> 4) * 8];
      accS[fc] = mfma16(a, bb, accS[fc]);
    }
  }
  __syncthreads();
  // S' into Cs
  {
    int lr = w * 16 + ((lane >> 4) << 2);
    #pragma unroll
    for (int fc = 0; fc < 8; fc++){
      int s = fc * 16 + (lane & 15);
      #pragma unroll
      for (int j = 0; j < 4; j++){
        int l = l0 + lr + j;
        float v = (s <= l) ? accS[fc][j] * expf(ac[l] - ac[s]) : 0.f;
        Cs[lr + j][s] = f2b(v);
      }
    }
  }
  // XT = (x*dt)^T into Bs rows 0..63
  #pragma unroll
  for (int p = 0; p < 8; p++){
    int lr = p * 16 + (tid >> 4);
    int p4 = (tid & 15) * 4;
    float dtl = dtb[(rowbase + lr) * NH + hh];
    u16x4 v = *(const u16x4*)&xbc[(rowbase + lr) * CONVD + hh * HD + p4];
    Bs[p4 + 0][lr] = f2b(b2f(v[0]) * dtl);
    Bs[p4 + 1][lr] = f2b(b2f(v[1]) * dtl);
    Bs[p4 + 2][lr] = f2b(b2f(v[2]) * dtl);
    Bs[p4 + 3][lr] = f2b(b2f(v[3]) * dtl);
  }
  __syncthreads();
  f32x4 accY[4] = {};
  #pragma unroll
  for (int kk = 0; kk < 4; kk++){
    bf16x8 a = *(const bf16x8*)&Cs[w * 16 + (lane & 15)][kk * 32 + (lane >> 4) * 8];
    #pragma unroll
    for (int fc = 0; fc < 4; fc++){
      bf16x8 bb = *(const bf16x8*)&Bs[fc * 16 + (lane & 15)][kk * 32 + (lane >> 4) * 8];
      accY[fc] = mfma16(a, bb, accY[fc]);
    }
  }
  {
    int lr = w * 16 + ((lane >> 4) << 2);
    #pragma unroll
    for (int fc = 0; fc < 4; fc++){
      int p = fc * 16 + (lane & 15);
      #pragma unroll
      for (int j = 0; j < 4; j++){
        y[(rowbase + l0 + lr + j) * DINNER + hh * HD + p] = accY[fc][j];
      }
    }
  }
}

// ---------------- SSD part 2: states[p][n] = sum_l (x*dt*decay)[l][p] * B[l][n] ----------------
__global__ __launch_bounds__(256) void ssd_states_kernel(const unsigned short* __restrict__ xbc,
                                                         const float* __restrict__ dtb,
                                                         const float* __restrict__ acum,
                                                         unsigned short* __restrict__ states)
{
  int hh = blockIdx.x, c = blockIdx.y, b = blockIdx.z;
  __shared__ unsigned short BsT[128][136];  // [n][l]
  __shared__ unsigned short XT[64][136];    // [p][l]
  __shared__ float ac[128];
  int tid = threadIdx.x, lane = tid & 63, w = tid >> 6;
  size_t rowbase = (size_t)b * LTOT + c * CHUNK_;
  if (tid < 128) ac[tid] = acum[((size_t)(b * NH + hh)) * LTOT + c * CHUNK_ + tid];
  #pragma unroll
  for (int p = 0; p < 16; p++){
    int l = p * 8 + (tid >> 5);
    int n4 = (tid & 31) * 4;
    u16x4 v = *(const u16x4*)&xbc[(rowbase + l) * CONVD + DINNER + n4];
    BsT[n4 + 0][l] = v[0];
    BsT[n4 + 1][l] = v[1];
    BsT[n4 + 2][l] = v[2];
    BsT[n4 + 3][l] = v[3];
  }
  #pragma unroll
  for (int p = 0; p < 8; p++){
    int l = p * 16 + (tid >> 4);
    int p4 = (tid & 15) * 4;
    float dtl = dtb[(rowbase + l) * NH + hh];
    u16x4 v = *(const u16x4*)&xbc[(rowbase + l) * CONVD + hh * HD + p4];
    XT[p4 + 0][l] = f2b(b2f(v[0]) * dtl);
    XT[p4 + 1][l] = f2b(b2f(v[1]) * dtl);
    XT[p4 + 2][l] = f2b(b2f(v[2]) * dtl);
    XT[p4 + 3][l] = f2b(b2f(v[3]) * dtl);
  }
  __syncthreads();
  float aclast = ac[127];
  f32x4 accP[8] = {};
  #pragma unroll
  for (int kk = 0; kk < 4; kk++){
    int kbase = kk * 32 + (lane >> 4) * 8;
    union { u16x4 q[2]; unsigned short u[8]; bf16x8 v; } rw, ot;
    rw.q[0] = *(const u16x4*)&XT[w * 16 + (lane & 15)][kbase];
    rw.q[1] = *(const u16x4*)&XT[w * 16 + (lane & 15)][kbase + 4];
    #pragma unroll
    for (int e = 0; e < 8; e++){
      ot.u[e] = f2b(b2f(rw.u[e]) * expf(aclast - ac[kbase + e]));
    }
    #pragma unroll
    for (int fc = 0; fc < 8; fc++){
      bf16x8 bb = *(const bf16x8*)&BsT[fc * 16 + (lane & 15)][kbase];
      accP[fc] = mfma16(ot.v, bb, accP[fc]);
    }
  }
  size_t sbase = ((size_t)((b * NCH + c) * NH + hh)) * HD * DSTATE;
  int p0 = w * 16 + ((lane >> 4) << 2);
  #pragma unroll
  for (int fc = 0; fc < 8; fc++){
    int n = fc * 16 + (lane & 15);
    #pragma unroll
    for (int j = 0; j < 4; j++){
      states[sbase + (size_t)(p0 + j) * DSTATE + n] = f2b(accP[fc][j]);
    }
  }
}

// ---------------- SSD part 3: inter-chunk scan, in-place states -> prev ----------------
__global__ __launch_bounds__(256) void scan_kernel(unsigned short* __restrict__ states,
                                                   const float* __restrict__ acum)
{
  int bh = blockIdx.x;           // b*NH + h
  int b = bh >> 6, hh = bh & 63;
  int t = threadIdx.x;
  float run[32];
  #pragma unroll
  for (int j = 0; j < 32; j++) run[j] = 0.f;
  for (int c = 0; c < NCH; c++){
    float alast = acum[(size_t)bh * LTOT + c * CHUNK_ + 127];
    float dec = expf(alast);
    size_t base = ((size_t)((b * NCH + c) * NH + hh)) * (HD * DSTATE);
    #pragma unroll
    for (int j = 0; j < 32; j++){
      size_t idx = base + (size_t)j * 256 + t;
      float sc = b2f(states[idx]);
      states[idx] = f2b(run[j]);
      run[j] = run[j] * dec + sc;
    }
  }
}

// ---------------- SSD part 4: Y_off = decay[l] * C·prev^T, plus D*x, added into y ----------------
__global__ __launch_bounds__(256) void ssd3_kernel(const unsigned short* __restrict__ xbc,
                                                   const unsigned short* __restrict__ states,
                                                   const float* __restrict__ acum,
                                                   const float* __restrict__ Dp,
                                                   float* __restrict__ y)
{
  int hh = blockIdx.x, c = blockIdx.y, b = blockIdx.z;
  __shared__ unsigned short Cs[128][136];
  __shared__ unsigned short Ps[64][136];   // prev [p][n]
  __shared__ float ac[128];
  int tid = threadIdx.x, lane = tid & 63, w = tid >> 6;
  size_t rowbase = (size_t)b * LTOT + c * CHUNK_;
  if (tid < 128) ac[tid] = acum[((size_t)(b * NH + hh)) * LTOT + c * CHUNK_ + tid];
  #pragma unroll
  for (int p = 0; p < 16; p++){
    int l = p * 8 + (tid >> 5);
    int n4 = (tid & 31) * 4;
    *(u16x4*)&Cs[l][n4] =
      *(const u16x4*)&xbc[(rowbase + l) * CONVD + DINNER + DSTATE + n4];
  }
  size_t sbase = ((size_t)((b * NCH + c) * NH + hh)) * (HD * DSTATE);
  #pragma unroll
  for (int p = 0; p < 8; p++){
    int pp = p * 8 + (tid >> 5);
    int n4 = (tid & 31) * 4;
    *(u16x4*)&Ps[pp][n4] = *(const u16x4*)&states[sbase + (size_t)pp * DSTATE + n4];
  }
  __syncthreads();
  f32x4 acc[2][4] = {};
  #pragma unroll
  for (int kk = 0; kk < 4; kk++){
    bf16x8 a0 = *(const bf16x8*)&Cs[w * 32 + (lane & 15)][kk * 32 + (lane >> 4) * 8];
    bf16x8 a1 = *(const bf16x8*)&Cs[w * 32 + 16 + (lane & 15)][kk * 32 + (lane >> 4) * 8];
    #pragma unroll
    for (int fc = 0; fc < 4; fc++){
      bf16x8 bb = *(const bf16x8*)&Ps[fc * 16 + (lane & 15)][kk * 32 + (lane >> 4) * 8];
      acc[0][fc] = mfma16(a0, bb, acc[0][fc]);
      acc[1][fc] = mfma16(a1, bb, acc[1][fc]);
    }
  }
  float dpar = Dp[hh];
  #pragma unroll
  for (int fr = 0; fr < 2; fr++){
    int lr = w * 32 + fr * 16 + ((lane >> 4) << 2);
    #pragma unroll
    for (int fc = 0; fc < 4; fc++){
      int p = fc * 16 + (lane & 15);
      #pragma unroll
      for (int j = 0; j < 4; j++){
        int l = lr + j;
        size_t yi = (rowbase + l) * DINNER + hh * HD + p;
        float xsv = b2f(xbc[(rowbase + l) * CONVD + hh * HD + p]);
        y[yi] += acc[fr][fc][j] * expf(ac[l]) + dpar * xsv;
      }
    }
  }
}

extern "C" void kernel_launch(void* const* d_in, const int* in_sizes, int n_in,
                              void* d_out, int out_size, void* d_ws, size_t ws_size,
                              hipStream_t stream)
{
  (void)in_sizes; (void)n_in; (void)out_size; (void)ws_size;
  const float* hidden    = (const float*)d_in[0];
  const float* norm1_w   = (const float*)d_in[1];
  const float* in_proj_w = (const float*)d_in[2];
  const float* conv_w    = (const float*)d_in[3];
  const float* conv_b    = (const float*)d_in[4];
  const float* dt_bias   = (const float*)d_in[5];
  const float* A_log     = (const float*)d_in[6];
  const float* D_param   = (const float*)d_in[7];
  const float* mixer_w   = (const float*)d_in[8];
  const float* out_proj_w= (const float*)d_in[9];
  const float* norm2_w   = (const float*)d_in[10];
  const float* gate_w    = (const float*)d_in[11];
  const float* up_w      = (const float*)d_in[12];
  const float* down_w    = (const float*)d_in[13];

  char* ws = (char*)d_ws;
  // Workspace layout (total 175,636,480 bytes), live-range-verified aliases.
  unsigned short* zbuf    = (unsigned short*)(ws);                  // bf16 4096x4096 [k2..k10]
  unsigned short* WT_gate = (unsigned short*)(ws);                  // bf16 5632x2048 [k12.5..k13] (zbuf dead)
  unsigned short* xdt     = (unsigned short*)(ws + 33554432ull);    // bf16 4096x4416 [k2..k5]
  unsigned short* states  = (unsigned short*)(ws + 33554432ull);    // bf16 16.7M el  [k7..k9]
  unsigned short* ygn     = (unsigned short*)(ws + 33554432ull);    // bf16 4096x4096 [k10..k11]
  unsigned short* WT_up   = (unsigned short*)(ws + 33554432ull);    // bf16 5632x2048 [k13.5..k14]
  unsigned short* xbc     = (unsigned short*)(ws + 69730304ull);    // bf16 4096x4352 [k5..k9]
  unsigned short* WT_out  = (unsigned short*)(ws + 69730304ull);    // bf16 2048x4096 [k10.5..k11]
  unsigned short* h2      = (unsigned short*)(ws + 69730304ull);    // bf16 4096x2048 [k12..k14]
  unsigned short* WT_down = (unsigned short*)(ws + 69730304ull);    // bf16 2048x5632 [k14.5..k15]
  float* dtraw            = (float*)(ws + 105381888ull);            // f32 4096x64 [k2..k3]
  float* dtb              = (float*)(ws + 106430464ull);            // f32 4096x64 [k3..k9]
  float* acum             = (float*)(ws + 107479040ull);            // f32 128x2048 [k4..k9]
  float* ybuf             = (float*)(ws + 108527616ull);            // f32 4096x4096 [k6..k10]
  unsigned short* hbuf    = (unsigned short*)(ws + 108527616ull);   // bf16 4096x2048 [k1..k2]
  unsigned short* gbuf    = (unsigned short*)(ws + 108527616ull);   // bf16 4096x5632 [k13..k16]
  unsigned short* WT_in   = (unsigned short*)(ws + 125304832ull);   // bf16 8704x2048 [k0..k2] (in ybuf tail, ends 160.96MB)
  float* h1               = (float*)d_out;                          // f32 4096x2048 [k11..k16]
  float* outp             = (float*)d_out;

  const int dynLDS = 131072;
  hipFuncSetAttribute((const void*)gemm2_kernel,
                      hipFuncAttributeMaxDynamicSharedMemorySize, dynLDS);

  // 0. convert in_proj weight -> bf16 [8704][2048] (rows >= 8512 zeroed; 8704 = 34*256)
  wconv_kernel<<<dim3(136, 32), 256, 0, stream>>>(in_proj_w, WT_in, DMODEL, INP);
  // 1. h = rmsnorm(hidden) -> bf16
  rms_kernel<<<NTOK, 256, 0, stream>>>(hidden, norm1_w, hbuf, DMODEL);
  // 2. zxbcdt = h @ in_proj: cols<4096 -> zbuf, cols>=4096 -> xdt; dt cols fp32 -> dtraw
  gemm2_kernel<<<dim3(34, 16), 512, dynLDS, stream>>>(hbuf, WT_in, nullptr, nullptr,
                                                      zbuf, xdt, DINNER, nullptr, dtraw,
                                                      NTOK, INP, DMODEL);
  // 3. dt = softplus(dtraw + bias)
  dt_kernel<<<NTOK * NH / 256, 256, 0, stream>>>(dtraw, dt_bias, dtb);
  // 4. per-chunk cumsum of dt*A
  acum_kernel<<<BATCH * NH * NCH, 64, 0, stream>>>(dtb, A_log, acum);
  // 5. conv + silu
  conv_kernel<<<dim3(CONVD / 256, LTOT, BATCH), 256, 0, stream>>>(xdt, conv_w, conv_b, xbc);
  // 6. SSD intra-chunk: Y_diag
  ssd_sy_kernel<<<dim3(NH, NCH * 2, BATCH), 256, 0, stream>>>(xbc, dtb, acum, ybuf);
  // 7. SSD per-chunk states
  ssd_states_kernel<<<dim3(NH, NCH, BATCH), 256, 0, stream>>>(xbc, dtb, acum, states);
  // 8. inter-chunk scan (in-place -> prev)
  scan_kernel<<<BATCH * NH, 256, 0, stream>>>(states, acum);
  // 9. SSD off-diagonal + D*x
  ssd3_kernel<<<dim3(NH, NCH, BATCH), 256, 0, stream>>>(xbc, states, acum, D_param, ybuf);
  // 10. gated rmsnorm: ygn = rmsnorm(y * silu(z))
  rms_gated_kernel<<<NTOK, 256, 0, stream>>>(ybuf, zbuf, mixer_w, ygn);
  // 10.5 convert out_proj weight (xbc region dead)
  wconv_kernel<<<dim3(32, 64), 256, 0, stream>>>(out_proj_w, WT_out, DINNER, DMODEL);
  // 11. h1 = hidden + ygn @ out_proj  (into d_out)
  gemm2_kernel<<<dim3(8, 16), 512, dynLDS, stream>>>(ygn, WT_out, hidden, h1,
                                                     nullptr, nullptr, 0, nullptr, nullptr,
                                                     NTOK, DMODEL, DINNER);
  // 12. h2 = rmsnorm(h1) -> bf16
  rms_kernel<<<NTOK, 256, 0, stream>>>(h1, norm2_w, h2, DMODEL);
  // 12.5 convert gate weight (zbuf dead)
  wconv_kernel<<<dim3(88, 32), 256, 0, stream>>>(gate_w, WT_gate, DMODEL, INTER_);
  // 13. g = h2 @ gate_w -> gbuf (bf16)
  gemm2_kernel<<<dim3(22, 16), 512, dynLDS, stream>>>(h2, WT_gate, nullptr, nullptr,
                                                      gbuf, nullptr, INTER_, nullptr, nullptr,
                                                      NTOK, INTER_, DMODEL);
  // 13.5 convert up weight (xdt/ygn dead)
  wconv_kernel<<<dim3(88, 32), 256, 0, stream>>>(up_w, WT_up, DMODEL, INTER_);
  // 14. u = h2 @ up_w, fused: gbuf = silu(gbuf) * u
  gemm2_kernel<<<dim3(22, 16), 512, dynLDS, stream>>>(h2, WT_up, nullptr, nullptr,
                                                      gbuf, nullptr, INTER_, gbuf, nullptr,
                                                      NTOK, INTER_, DMODEL);
  // 14.5 convert down weight (h2 dead)
  wconv_kernel<<<dim3(32, 88), 256, 0, stream>>>(down_w, WT_down, INTER_, DMODEL);
  // 15. out = h1 + (g*u) @ down_w  (in place on d_out)
  gemm2_kernel<<<dim3(8, 16), 512, dynLDS, stream>>>(gbuf, WT_down, h1, outp,
                                                     nullptr, nullptr, 0, nullptr, nullptr,
                                                     NTOK, DMODEL, INTER_);
}

// Round 6
// 1112.450 us; speedup vs baseline: 1.2277x; 1.2277x over previous
//
#include <hip/hip_runtime.h>

#define LTOT 2048
#define BATCH 2
#define NTOK 4096
#define DMODEL 2048
#define DSTATE 128
#define NH 64
#define HD 64
#define DINNER 4096
#define CONVD 4352
#define XDTC 4416
#define INP 8512
#define INTER_ 5632
#define CHUNK_ 128
#define NCH 16
#define EPSF 1e-6f

typedef __bf16 bf16x8 __attribute__((ext_vector_type(8)));
typedef float f32x4 __attribute__((ext_vector_type(4)));
typedef unsigned short u16x4 __attribute__((ext_vector_type(4)));
typedef unsigned short u16x8 __attribute__((ext_vector_type(8)));

__device__ __forceinline__ unsigned short f2b(float f){
  unsigned int u = __builtin_bit_cast(unsigned int, f);
  u += 0x7fffu + ((u >> 16) & 1u);
  return (unsigned short)(u >> 16);
}
__device__ __forceinline__ float b2f(unsigned short h){
  return __builtin_bit_cast(float, ((unsigned int)h) << 16);
}
__device__ __forceinline__ f32x4 mfma16(bf16x8 a, bf16x8 b, f32x4 c){
  return __builtin_amdgcn_mfma_f32_16x16x32_bf16(a, b, c, 0, 0, 0);
}
// async global->LDS, 16B per lane, wave-uniform LDS base + lane*16
typedef const __attribute__((address_space(1))) void* gas_t;
typedef __attribute__((address_space(3))) void* las_t;
__device__ __forceinline__ void gload16(const void* g, void* l){
  __builtin_amdgcn_global_load_lds((gas_t)g, (las_t)l, 16, 0, 0);
}

// ---------------- weight convert: fp32 W[K][N] -> bf16 WT[Npad][K], zero rows n>=N ----------------
__global__ __launch_bounds__(256) void wconv_kernel(const float* __restrict__ W,
                                                    unsigned short* __restrict__ WT,
                                                    int K, int N)
{
  __shared__ unsigned short t[64][72];
  int n0 = blockIdx.x * 64, k0 = blockIdx.y * 64;
  int tid = threadIdx.x;
  int kl = tid >> 4, nl4 = (tid & 15) * 4;
  #pragma unroll
  for (int it = 0; it < 4; it++){
    int kk = kl + it * 16;
    float4 v = make_float4(0.f, 0.f, 0.f, 0.f);
    if (n0 < N) v = *(const float4*)&W[(size_t)(k0 + kk) * N + n0 + nl4];
    t[nl4 + 0][kk] = f2b(v.x);
    t[nl4 + 1][kk] = f2b(v.y);
    t[nl4 + 2][kk] = f2b(v.z);
    t[nl4 + 3][kk] = f2b(v.w);
  }
  __syncthreads();
  int nr = tid >> 3, k8 = (tid & 7) * 8;
  #pragma unroll
  for (int it = 0; it < 2; it++){
    int nn = nr + it * 32;
    *(u16x8*)&WT[(size_t)(n0 + nn) * K + k0 + k8] = *(const u16x8*)&t[nn][k8];
  }
}

// ---------------- RMSNorm: fp32 in -> bf16 out ----------------
__global__ __launch_bounds__(256) void rms_kernel(const float* __restrict__ x,
                                                  const float* __restrict__ w,
                                                  unsigned short* __restrict__ out, int width)
{
  int row = blockIdx.x, tid = threadIdx.x;
  const float* xr = x + (size_t)row * width;
  unsigned short* orow = out + (size_t)row * width;
  int nv = width >> 2;
  float ss = 0.f;
  for (int i = tid; i < nv; i += 256){
    float4 v = ((const float4*)xr)[i];
    ss += v.x*v.x + v.y*v.y + v.z*v.z + v.w*v.w;
  }
  #pragma unroll
  for (int off = 32; off > 0; off >>= 1) ss += __shfl_down(ss, off, 64);
  __shared__ float red[4];
  if ((tid & 63) == 0) red[tid >> 6] = ss;
  __syncthreads();
  float tot = red[0] + red[1] + red[2] + red[3];
  float scale = rsqrtf(tot / (float)width + EPSF);
  for (int i = tid; i < nv; i += 256){
    float4 v = ((const float4*)xr)[i];
    float4 wv = ((const float4*)w)[i];
    u16x4 o = { f2b(v.x * scale * wv.x), f2b(v.y * scale * wv.y),
                f2b(v.z * scale * wv.z), f2b(v.w * scale * wv.w) };
    ((u16x4*)orow)[i] = o;
  }
}

// ---------------- Gated RMSNorm: y fp32, z bf16 -> out bf16 ----------------
__global__ __launch_bounds__(256) void rms_gated_kernel(const float* __restrict__ y,
                                                        const unsigned short* __restrict__ z,
                                                        const float* __restrict__ w,
                                                        unsigned short* __restrict__ out)
{
  int row = blockIdx.x, tid = threadIdx.x;
  const float* yr = y + (size_t)row * DINNER;
  const unsigned short* zr = z + (size_t)row * DINNER;
  unsigned short* orow = out + (size_t)row * DINNER;
  float g[16];
  float ss = 0.f;
  #pragma unroll
  for (int ii = 0; ii < 4; ii++){
    int i = tid + ii * 256;
    float4 yv = ((const float4*)yr)[i];
    u16x4 zv = ((const u16x4*)zr)[i];
    #pragma unroll
    for (int e = 0; e < 4; e++){
      float zf = b2f(zv[e]);
      float yf = (&yv.x)[e];
      float gg = yf * (zf / (1.f + expf(-zf)));
      g[ii * 4 + e] = gg;
      ss += gg * gg;
    }
  }
  #pragma unroll
  for (int off = 32; off > 0; off >>= 1) ss += __shfl_down(ss, off, 64);
  __shared__ float red[4];
  if ((tid & 63) == 0) red[tid >> 6] = ss;
  __syncthreads();
  float tot = red[0] + red[1] + red[2] + red[3];
  float scale = rsqrtf(tot / (float)DINNER + EPSF);
  #pragma unroll
  for (int ii = 0; ii < 4; ii++){
    int i = tid + ii * 256;
    float4 wv = ((const float4*)w)[i];
    u16x4 o;
    #pragma unroll
    for (int e = 0; e < 4; e++) o[e] = f2b(g[ii * 4 + e] * scale * (&wv.x)[e]);
    ((u16x4*)orow)[i] = o;
  }
}

// ---------------- GEMM3: 128(M)x256(N) tile, BK=64, 8 waves, 3-buffer counted-vmcnt pipeline ----
// C = A(bf16,[M][K]) * BT(bf16,[Npad][K])^T. Dynamic LDS 144KB = 3 bufs x (A 16KB + B 32KB).
// 2-tile-deep prefetch: tile t+2's 6 loads/thread issued 3+3 in tile t's phases; the per-tile
// wait is vmcnt(6) (t+1 landed, t+2 in flight) — never drains to 0 mid-loop (T4).
// k-XOR swizzle (0 bank conflicts, verified R4); XCD-aware bijective block swizzle; setprio (T5).
__global__ __launch_bounds__(512, 1) void gemm3_kernel(const unsigned short* __restrict__ A,
                                                       const unsigned short* __restrict__ BT,
                                                       const float* __restrict__ addsrc,
                                                       float* __restrict__ Cf,
                                                       unsigned short* __restrict__ Cb,
                                                       unsigned short* __restrict__ Cb2, int splitN,
                                                       const unsigned short* __restrict__ gate,
                                                       float* __restrict__ dtraw,
                                                       int M, int N, int K)
{
  extern __shared__ unsigned short lds[];    // 73728 u16 = 144 KB; buf i at i*24576 (A 8192, B 16384)
  int tid = threadIdx.x, lane = tid & 63, w = tid >> 6;
  int wm = w >> 2, wn = w & 3;               // wave grid 2(M) x 4(N); wave block 64x64
  int bid = blockIdx.x + blockIdx.y * gridDim.x;
  int nwg = gridDim.x * gridDim.y;
  int q8 = nwg >> 3, r8 = nwg & 7;
  int xcd = bid & 7, boff = bid >> 3;
  int wgid = (xcd < r8 ? xcd * (q8 + 1) : r8 * (q8 + 1) + (xcd - r8) * q8) + boff;
  int bn = (wgid % gridDim.x) * 256;
  int bm = (wgid / gridDim.x) * 128;

  int srow = lane >> 3;                      // row within 8-row wave-stripe
  int sk   = ((lane & 7) ^ srow) << 3;       // pre-swizzled source k-offset
  int kswz = (lane & 7) << 3;                // read-side XOR (frag row&7 == lane&7)

  f32x4 acc[4][4] = {};
  int NT = K >> 6;

  // prologue: stage tiles 0 and 1 (6 loads/thread each: 2 A-chunks + 4 B-chunks of 64 rows)
  #pragma unroll
  for (int pt = 0; pt < 2; ++pt){
    unsigned short* bA = &lds[pt * 24576];
    unsigned short* bB = bA + 8192;
    size_t k0 = (size_t)pt << 6;
    #pragma unroll
    for (int a = 0; a < 2; ++a)
      gload16(&A [(size_t)(bm + a * 64 + w * 8 + srow) * K + k0 + sk], &bA[(a * 8 + w) * 512]);
    #pragma unroll
    for (int b = 0; b < 4; ++b)
      gload16(&BT[(size_t)(bn + b * 64 + w * 8 + srow) * K + k0 + sk], &bB[(b * 8 + w) * 512]);
  }
  asm volatile("s_waitcnt vmcnt(6)" ::: "memory");   // tile 0 landed; tile 1 in flight
  __builtin_amdgcn_s_barrier();
  asm volatile("" ::: "memory");

  for (int t = 0; t < NT; ++t){
    unsigned short* bA = &lds[(t % 3) * 24576];
    unsigned short* bB = bA + 8192;
    int t2 = t + 2;
    unsigned short* nA = &lds[(t2 % 3) * 24576];
    unsigned short* nB = nA + 8192;
    size_t k2 = (size_t)t2 << 6;
    bool pf = t2 < NT;
    bf16x8 bfr[2][4];
    #pragma unroll
    for (int q = 0; q < 2; ++q){
      // ds-reads first (m201 order): B frags once per tile (phase 0), A frags per phase
      bf16x8 afr[2][2];
      #pragma unroll
      for (int kk2 = 0; kk2 < 2; ++kk2){
        int kcol = (kk2 * 32 + (lane >> 4) * 8) ^ kswz;
        if (q == 0){
          #pragma unroll
          for (int c = 0; c < 4; ++c)
            bfr[kk2][c] = *(const bf16x8*)&bB[(wn * 64 + c * 16 + (lane & 15)) * 64 + kcol];
        }
        #pragma unroll
        for (int r = 0; r < 2; ++r)
          afr[kk2][r] = *(const bf16x8*)&bA[(wm * 64 + q * 32 + r * 16 + (lane & 15)) * 64 + kcol];
      }
      // stage tile t+2 (3 loads this phase); its buffer was fully consumed at end of tile t-1
      if (pf){
        if (q == 0){
          gload16(&A [(size_t)(bm +       w * 8 + srow) * K + k2 + sk], &nA[w * 512]);
          gload16(&BT[(size_t)(bn +       w * 8 + srow) * K + k2 + sk], &nB[w * 512]);
          gload16(&BT[(size_t)(bn +  64 + w * 8 + srow) * K + k2 + sk], &nB[(8 + w) * 512]);
        } else {
          gload16(&A [(size_t)(bm +  64 + w * 8 + srow) * K + k2 + sk], &nA[(8 + w) * 512]);
          gload16(&BT[(size_t)(bn + 128 + w * 8 + srow) * K + k2 + sk], &nB[(16 + w) * 512]);
          gload16(&BT[(size_t)(bn + 192 + w * 8 + srow) * K + k2 + sk], &nB[(24 + w) * 512]);
        }
      }
      asm volatile("" ::: "memory");
      __builtin_amdgcn_s_barrier();
      asm volatile("s_waitcnt lgkmcnt(0)" ::: "memory");
      __builtin_amdgcn_s_setprio(1);
      #pragma unroll
      for (int kk2 = 0; kk2 < 2; ++kk2)
        #pragma unroll
        for (int r = 0; r < 2; ++r)
          #pragma unroll
          for (int c = 0; c < 4; ++c)
            acc[q * 2 + r][c] = mfma16(afr[kk2][r], bfr[kk2][c], acc[q * 2 + r][c]);
      __builtin_amdgcn_s_setprio(0);
      if (q == 1){
        if (t + 2 < NT)      asm volatile("s_waitcnt vmcnt(6)" ::: "memory");  // t+1 landed
        else if (t + 1 < NT) asm volatile("s_waitcnt vmcnt(0)" ::: "memory");  // boundary drain
      }
      asm volatile("" ::: "memory");
      __builtin_amdgcn_s_barrier();
      asm volatile("" ::: "memory");
    }
  }

  // epilogue (no LDS use)
  int r0 = bm + wm * 64 + ((lane >> 4) << 2);
  int c0 = bn + wn * 64 + (lane & 15);
  #pragma unroll
  for (int i = 0; i < 4; ++i){
    #pragma unroll
    for (int j = 0; j < 4; ++j){
      int cc = c0 + j * 16;
      if (cc < N){
        #pragma unroll
        for (int e = 0; e < 4; ++e){
          int rr = r0 + i * 16 + e;
          float v = acc[i][j][e];
          if (Cf){
            size_t idx = (size_t)rr * N + cc;
            if (addsrc) v += addsrc[idx];
            Cf[idx] = v;
          } else if (cc < splitN){
            size_t idx = (size_t)rr * splitN + cc;
            float vv = v;
            if (gate){ float gg = b2f(gate[idx]); vv = gg / (1.f + expf(-gg)) * v; }
            Cb[idx] = f2b(vv);
          } else {
            Cb2[(size_t)rr * (N - splitN) + (cc - splitN)] = f2b(v);
            if (dtraw && cc >= N - NH) dtraw[(size_t)rr * NH + (cc - (N - NH))] = v;
          }
        }
      }
    }
  }
}

// ---------------- dt = softplus(dtraw + dt_bias), fp32 path ----------------
__global__ __launch_bounds__(256) void dt_kernel(const float* __restrict__ dtraw,
                                                 const float* __restrict__ dt_bias,
                                                 float* __restrict__ dtb)
{
  int idx = blockIdx.x * 256 + threadIdx.x;
  float raw = dtraw[idx] + dt_bias[idx & 63];
  dtb[idx] = (raw > 20.f) ? raw : log1pf(expf(raw));
}

// ---------------- per (b,h,c) inclusive cumsum of dA = dt*A within chunk ----------------
__global__ __launch_bounds__(64) void acum_kernel(const float* __restrict__ dtb,
                                                  const float* __restrict__ A_log,
                                                  float* __restrict__ acum)
{
  int bid = blockIdx.x;          // (b*NH + h)*NCH + c
  int c = bid & 15;
  int hh = (bid >> 4) & 63;
  int b = bid >> 10;
  int lane = threadIdx.x;
  float Av = -expf(A_log[hh]);
  int rowbase = b * LTOT + c * CHUNK_;
  float v0 = dtb[(size_t)(rowbase + 2 * lane) * NH + hh] * Av;
  float v1 = dtb[(size_t)(rowbase + 2 * lane + 1) * NH + hh] * Av;
  float s = v0 + v1;
  #pragma unroll
  for (int d = 1; d < 64; d <<= 1){
    float t = __shfl_up(s, d, 64);
    if (lane >= d) s += t;
  }
  float excl = s - (v0 + v1);
  float* dst = acum + ((size_t)(b * NH + hh)) * LTOT + c * CHUNK_;
  dst[2 * lane]     = excl + v0;
  dst[2 * lane + 1] = excl + v0 + v1;
}

// ---------------- depthwise causal conv (width 4) + bias + SiLU, bf16 in/out ----------------
__global__ __launch_bounds__(256) void conv_kernel(const unsigned short* __restrict__ xdt,
                                                   const float* __restrict__ cw,
                                                   const float* __restrict__ cb,
                                                   unsigned short* __restrict__ xbc)
{
  int ch = blockIdx.x * 256 + threadIdx.x;   // 17*256 = 4352 = CONVD exactly
  int l = blockIdx.y, b = blockIdx.z;
  float acc = cb[ch];
  #pragma unroll
  for (int j = 0; j < 4; j++){
    int ls = l + j - 3;
    if (ls >= 0) acc += b2f(xdt[((size_t)(b * LTOT + ls)) * XDTC + ch]) * cw[ch * 4 + j];
  }
  acc = acc / (1.f + expf(-acc));
  xbc[((size_t)(b * LTOT + l)) * CONVD + ch] = f2b(acc);
}

// ---------------- SSD part 1: S' = (C·B^T)⊙L, Y_diag = S'·(x·dt)^T ----------------
__global__ __launch_bounds__(256) void ssd_sy_kernel(const unsigned short* __restrict__ xbc,
                                                     const float* __restrict__ dtb,
                                                     const float* __restrict__ acum,
                                                     float* __restrict__ y)
{
  int hh = blockIdx.x;
  int c = blockIdx.y >> 1;
  int half = blockIdx.y & 1;
  int b = blockIdx.z;
  __shared__ unsigned short Cs[64][136];    // C rows (l0..l0+63), later S'
  __shared__ unsigned short Bs[128][136];   // B rows (all s), later XT (rows 0..63 = p)
  __shared__ float ac[128];
  int tid = threadIdx.x, lane = tid & 63, w = tid >> 6;
  int l0 = half * 64;
  size_t rowbase = (size_t)b * LTOT + c * CHUNK_;
  if (tid < 128) ac[tid] = acum[((size_t)(b * NH + hh)) * LTOT + c * CHUNK_ + tid];
  #pragma unroll
  for (int p = 0; p < 8; p++){
    int lr = p * 8 + (tid >> 5);
    int n4 = (tid & 31) * 4;
    *(u16x4*)&Cs[lr][n4] =
      *(const u16x4*)&xbc[(rowbase + l0 + lr) * CONVD + DINNER + DSTATE + n4];
  }
  #pragma unroll
  for (int p = 0; p < 16; p++){
    int s = p * 8 + (tid >> 5);
    int n4 = (tid & 31) * 4;
    *(u16x4*)&Bs[s][n4] = *(const u16x4*)&xbc[(rowbase + s) * CONVD + DINNER + n4];
  }
  __syncthreads();
  f32x4 accS[8] = {};
  #pragma unroll
  for (int kk = 0; kk < 4; kk++){
    bf16x8 a = *(const bf16x8*)&Cs[w * 16 + (lane & 15)][kk * 32 + (lane >> 4) * 8];
    #pragma unroll
    for (int fc = 0; fc < 8; fc++){
      bf16x8 bb = *(const bf16x8*)&Bs[fc * 16 + (lane & 15)][kk * 32 + (lane >> 4) * 8];
      accS[fc] = mfma16(a, bb, accS[fc]);
    }
  }
  __syncthreads();
  // S' into Cs
  {
    int lr = w * 16 + ((lane >> 4) << 2);
    #pragma unroll
    for (int fc = 0; fc < 8; fc++){
      int s = fc * 16 + (lane & 15);
      #pragma unroll
      for (int j = 0; j < 4; j++){
        int l = l0 + lr + j;
        float v = (s <= l) ? accS[fc][j] * expf(ac[l] - ac[s]) : 0.f;
        Cs[lr + j][s] = f2b(v);
      }
    }
  }
  // XT = (x*dt)^T into Bs rows 0..63
  #pragma unroll
  for (int p = 0; p < 8; p++){
    int lr = p * 16 + (tid >> 4);
    int p4 = (tid & 15) * 4;
    float dtl = dtb[(rowbase + lr) * NH + hh];
    u16x4 v = *(const u16x4*)&xbc[(rowbase + lr) * CONVD + hh * HD + p4];
    Bs[p4 + 0][lr] = f2b(b2f(v[0]) * dtl);
    Bs[p4 + 1][lr] = f2b(b2f(v[1]) * dtl);
    Bs[p4 + 2][lr] = f2b(b2f(v[2]) * dtl);
    Bs[p4 + 3][lr] = f2b(b2f(v[3]) * dtl);
  }
  __syncthreads();
  f32x4 accY[4] = {};
  #pragma unroll
  for (int kk = 0; kk < 4; kk++){
    bf16x8 a = *(const bf16x8*)&Cs[w * 16 + (lane & 15)][kk * 32 + (lane >> 4) * 8];
    #pragma unroll
    for (int fc = 0; fc < 4; fc++){
      bf16x8 bb = *(const bf16x8*)&Bs[fc * 16 + (lane & 15)][kk * 32 + (lane >> 4) * 8];
      accY[fc] = mfma16(a, bb, accY[fc]);
    }
  }
  {
    int lr = w * 16 + ((lane >> 4) << 2);
    #pragma unroll
    for (int fc = 0; fc < 4; fc++){
      int p = fc * 16 + (lane & 15);
      #pragma unroll
      for (int j = 0; j < 4; j++){
        y[(rowbase + l0 + lr + j) * DINNER + hh * HD + p] = accY[fc][j];
      }
    }
  }
}

// ---------------- SSD part 2: states[p][n] = sum_l (x*dt*decay)[l][p] * B[l][n] ----------------
__global__ __launch_bounds__(256) void ssd_states_kernel(const unsigned short* __restrict__ xbc,
                                                         const float* __restrict__ dtb,
                                                         const float* __restrict__ acum,
                                                         unsigned short* __restrict__ states)
{
  int hh = blockIdx.x, c = blockIdx.y, b = blockIdx.z;
  __shared__ unsigned short BsT[128][136];  // [n][l]
  __shared__ unsigned short XT[64][136];    // [p][l]
  __shared__ float ac[128];
  int tid = threadIdx.x, lane = tid & 63, w = tid >> 6;
  size_t rowbase = (size_t)b * LTOT + c * CHUNK_;
  if (tid < 128) ac[tid] = acum[((size_t)(b * NH + hh)) * LTOT + c * CHUNK_ + tid];
  #pragma unroll
  for (int p = 0; p < 16; p++){
    int l = p * 8 + (tid >> 5);
    int n4 = (tid & 31) * 4;
    u16x4 v = *(const u16x4*)&xbc[(rowbase + l) * CONVD + DINNER + n4];
    BsT[n4 + 0][l] = v[0];
    BsT[n4 + 1][l] = v[1];
    BsT[n4 + 2][l] = v[2];
    BsT[n4 + 3][l] = v[3];
  }
  #pragma unroll
  for (int p = 0; p < 8; p++){
    int l = p * 16 + (tid >> 4);
    int p4 = (tid & 15) * 4;
    float dtl = dtb[(rowbase + l) * NH + hh];
    u16x4 v = *(const u16x4*)&xbc[(rowbase + l) * CONVD + hh * HD + p4];
    XT[p4 + 0][l] = f2b(b2f(v[0]) * dtl);
    XT[p4 + 1][l] = f2b(b2f(v[1]) * dtl);
    XT[p4 + 2][l] = f2b(b2f(v[2]) * dtl);
    XT[p4 + 3][l] = f2b(b2f(v[3]) * dtl);
  }
  __syncthreads();
  float aclast = ac[127];
  f32x4 accP[8] = {};
  #pragma unroll
  for (int kk = 0; kk < 4; kk++){
    int kbase = kk * 32 + (lane >> 4) * 8;
    union { u16x4 q[2]; unsigned short u[8]; bf16x8 v; } rw, ot;
    rw.q[0] = *(const u16x4*)&XT[w * 16 + (lane & 15)][kbase];
    rw.q[1] = *(const u16x4*)&XT[w * 16 + (lane & 15)][kbase + 4];
    #pragma unroll
    for (int e = 0; e < 8; e++){
      ot.u[e] = f2b(b2f(rw.u[e]) * expf(aclast - ac[kbase + e]));
    }
    #pragma unroll
    for (int fc = 0; fc < 8; fc++){
      bf16x8 bb = *(const bf16x8*)&BsT[fc * 16 + (lane & 15)][kbase];
      accP[fc] = mfma16(ot.v, bb, accP[fc]);
    }
  }
  size_t sbase = ((size_t)((b * NCH + c) * NH + hh)) * HD * DSTATE;
  int p0 = w * 16 + ((lane >> 4) << 2);
  #pragma unroll
  for (int fc = 0; fc < 8; fc++){
    int n = fc * 16 + (lane & 15);
    #pragma unroll
    for (int j = 0; j < 4; j++){
      states[sbase + (size_t)(p0 + j) * DSTATE + n] = f2b(accP[fc][j]);
    }
  }
}

// ---------------- SSD part 3: inter-chunk scan, in-place states -> prev ----------------
__global__ __launch_bounds__(256) void scan_kernel(unsigned short* __restrict__ states,
                                                   const float* __restrict__ acum)
{
  int bh = blockIdx.x;           // b*NH + h
  int b = bh >> 6, hh = bh & 63;
  int t = threadIdx.x;
  float run[32];
  #pragma unroll
  for (int j = 0; j < 32; j++) run[j] = 0.f;
  for (int c = 0; c < NCH; c++){
    float alast = acum[(size_t)bh * LTOT + c * CHUNK_ + 127];
    float dec = expf(alast);
    size_t base = ((size_t)((b * NCH + c) * NH + hh)) * (HD * DSTATE);
    #pragma unroll
    for (int j = 0; j < 32; j++){
      size_t idx = base + (size_t)j * 256 + t;
      float sc = b2f(states[idx]);
      states[idx] = f2b(run[j]);
      run[j] = run[j] * dec + sc;
    }
  }
}

// ---------------- SSD part 4: Y_off = decay[l] * C·prev^T, plus D*x, added into y ----------------
__global__ __launch_bounds__(256) void ssd3_kernel(const unsigned short* __restrict__ xbc,
                                                   const unsigned short* __restrict__ states,
                                                   const float* __restrict__ acum,
                                                   const float* __restrict__ Dp,
                                                   float* __restrict__ y)
{
  int hh = blockIdx.x, c = blockIdx.y, b = blockIdx.z;
  __shared__ unsigned short Cs[128][136];
  __shared__ unsigned short Ps[64][136];   // prev [p][n]
  __shared__ float ac[128];
  int tid = threadIdx.x, lane = tid & 63, w = tid >> 6;
  size_t rowbase = (size_t)b * LTOT + c * CHUNK_;
  if (tid < 128) ac[tid] = acum[((size_t)(b * NH + hh)) * LTOT + c * CHUNK_ + tid];
  #pragma unroll
  for (int p = 0; p < 16; p++){
    int l = p * 8 + (tid >> 5);
    int n4 = (tid & 31) * 4;
    *(u16x4*)&Cs[l][n4] =
      *(const u16x4*)&xbc[(rowbase + l) * CONVD + DINNER + DSTATE + n4];
  }
  size_t sbase = ((size_t)((b * NCH + c) * NH + hh)) * (HD * DSTATE);
  #pragma unroll
  for (int p = 0; p < 8; p++){
    int pp = p * 8 + (tid >> 5);
    int n4 = (tid & 31) * 4;
    *(u16x4*)&Ps[pp][n4] = *(const u16x4*)&states[sbase + (size_t)pp * DSTATE + n4];
  }
  __syncthreads();
  f32x4 acc[2][4] = {};
  #pragma unroll
  for (int kk = 0; kk < 4; kk++){
    bf16x8 a0 = *(const bf16x8*)&Cs[w * 32 + (lane & 15)][kk * 32 + (lane >> 4) * 8];
    bf16x8 a1 = *(const bf16x8*)&Cs[w * 32 + 16 + (lane & 15)][kk * 32 + (lane >> 4) * 8];
    #pragma unroll
    for (int fc = 0; fc < 4; fc++){
      bf16x8 bb = *(const bf16x8*)&Ps[fc * 16 + (lane & 15)][kk * 32 + (lane >> 4) * 8];
      acc[0][fc] = mfma16(a0, bb, acc[0][fc]);
      acc[1][fc] = mfma16(a1, bb, acc[1][fc]);
    }
  }
  float dpar = Dp[hh];
  #pragma unroll
  for (int fr = 0; fr < 2; fr++){
    int lr = w * 32 + fr * 16 + ((lane >> 4) << 2);
    #pragma unroll
    for (int fc = 0; fc < 4; fc++){
      int p = fc * 16 + (lane & 15);
      #pragma unroll
      for (int j = 0; j < 4; j++){
        int l = lr + j;
        size_t yi = (rowbase + l) * DINNER + hh * HD + p;
        float xsv = b2f(xbc[(rowbase + l) * CONVD + hh * HD + p]);
        y[yi] += acc[fr][fc][j] * expf(ac[l]) + dpar * xsv;
      }
    }
  }
}

extern "C" void kernel_launch(void* const* d_in, const int* in_sizes, int n_in,
                              void* d_out, int out_size, void* d_ws, size_t ws_size,
                              hipStream_t stream)
{
  (void)in_sizes; (void)n_in; (void)out_size; (void)ws_size;
  const float* hidden    = (const float*)d_in[0];
  const float* norm1_w   = (const float*)d_in[1];
  const float* in_proj_w = (const float*)d_in[2];
  const float* conv_w    = (const float*)d_in[3];
  const float* conv_b    = (const float*)d_in[4];
  const float* dt_bias   = (const float*)d_in[5];
  const float* A_log     = (const float*)d_in[6];
  const float* D_param   = (const float*)d_in[7];
  const float* mixer_w   = (const float*)d_in[8];
  const float* out_proj_w= (const float*)d_in[9];
  const float* norm2_w   = (const float*)d_in[10];
  const float* gate_w    = (const float*)d_in[11];
  const float* up_w      = (const float*)d_in[12];
  const float* down_w    = (const float*)d_in[13];

  char* ws = (char*)d_ws;
  // Workspace layout (total 175,636,480 bytes), live-range-verified aliases.
  unsigned short* zbuf    = (unsigned short*)(ws);                  // bf16 4096x4096 [k2..k10]
  unsigned short* WT_gate = (unsigned short*)(ws);                  // bf16 5632x2048 [k12.5..k13] (zbuf dead)
  unsigned short* xdt     = (unsigned short*)(ws + 33554432ull);    // bf16 4096x4416 [k2..k5]
  unsigned short* states  = (unsigned short*)(ws + 33554432ull);    // bf16 16.7M el  [k7..k9]
  unsigned short* ygn     = (unsigned short*)(ws + 33554432ull);    // bf16 4096x4096 [k10..k11]
  unsigned short* WT_up   = (unsigned short*)(ws + 33554432ull);    // bf16 5632x2048 [k13.5..k14]
  unsigned short* xbc     = (unsigned short*)(ws + 69730304ull);    // bf16 4096x4352 [k5..k9]
  unsigned short* WT_out  = (unsigned short*)(ws + 69730304ull);    // bf16 2048x4096 [k10.5..k11]
  unsigned short* h2      = (unsigned short*)(ws + 69730304ull);    // bf16 4096x2048 [k12..k14]
  unsigned short* WT_down = (unsigned short*)(ws + 69730304ull);    // bf16 2048x5632 [k14.5..k15]
  float* dtraw            = (float*)(ws + 105381888ull);            // f32 4096x64 [k2..k3]
  float* dtb              = (float*)(ws + 106430464ull);            // f32 4096x64 [k3..k9]
  float* acum             = (float*)(ws + 107479040ull);            // f32 128x2048 [k4..k9]
  float* ybuf             = (float*)(ws + 108527616ull);            // f32 4096x4096 [k6..k10]
  unsigned short* hbuf    = (unsigned short*)(ws + 108527616ull);   // bf16 4096x2048 [k1..k2]
  unsigned short* gbuf    = (unsigned short*)(ws + 108527616ull);   // bf16 4096x5632 [k13..k16]
  unsigned short* WT_in   = (unsigned short*)(ws + 125304832ull);   // bf16 8704x2048 [k0..k2]
  float* h1               = (float*)d_out;                          // f32 4096x2048 [k11..k16]
  float* outp             = (float*)d_out;

  const int dynLDS = 147456;   // 3 x 48KB
  hipFuncSetAttribute((const void*)gemm3_kernel,
                      hipFuncAttributeMaxDynamicSharedMemorySize, dynLDS);

  // 0. convert in_proj weight -> bf16 [8704][2048] (rows >= 8512 zeroed; 8704 = 34*256)
  wconv_kernel<<<dim3(136, 32), 256, 0, stream>>>(in_proj_w, WT_in, DMODEL, INP);
  // 1. h = rmsnorm(hidden) -> bf16
  rms_kernel<<<NTOK, 256, 0, stream>>>(hidden, norm1_w, hbuf, DMODEL);
  // 2. zxbcdt = h @ in_proj: cols<4096 -> zbuf, cols>=4096 -> xdt; dt cols fp32 -> dtraw
  gemm3_kernel<<<dim3(34, 32), 512, dynLDS, stream>>>(hbuf, WT_in, nullptr, nullptr,
                                                      zbuf, xdt, DINNER, nullptr, dtraw,
                                                      NTOK, INP, DMODEL);
  // 3. dt = softplus(dtraw + bias)
  dt_kernel<<<NTOK * NH / 256, 256, 0, stream>>>(dtraw, dt_bias, dtb);
  // 4. per-chunk cumsum of dt*A
  acum_kernel<<<BATCH * NH * NCH, 64, 0, stream>>>(dtb, A_log, acum);
  // 5. conv + silu
  conv_kernel<<<dim3(CONVD / 256, LTOT, BATCH), 256, 0, stream>>>(xdt, conv_w, conv_b, xbc);
  // 6. SSD intra-chunk: Y_diag
  ssd_sy_kernel<<<dim3(NH, NCH * 2, BATCH), 256, 0, stream>>>(xbc, dtb, acum, ybuf);
  // 7. SSD per-chunk states
  ssd_states_kernel<<<dim3(NH, NCH, BATCH), 256, 0, stream>>>(xbc, dtb, acum, states);
  // 8. inter-chunk scan (in-place -> prev)
  scan_kernel<<<BATCH * NH, 256, 0, stream>>>(states, acum);
  // 9. SSD off-diagonal + D*x
  ssd3_kernel<<<dim3(NH, NCH, BATCH), 256, 0, stream>>>(xbc, states, acum, D_param, ybuf);
  // 10. gated rmsnorm: ygn = rmsnorm(y * silu(z))
  rms_gated_kernel<<<NTOK, 256, 0, stream>>>(ybuf, zbuf, mixer_w, ygn);
  // 10.5 convert out_proj weight (xbc region dead)
  wconv_kernel<<<dim3(32, 64), 256, 0, stream>>>(out_proj_w, WT_out, DINNER, DMODEL);
  // 11. h1 = hidden + ygn @ out_proj  (into d_out); grid 8x32 = 256 blocks = 1/CU exact
  gemm3_kernel<<<dim3(8, 32), 512, dynLDS, stream>>>(ygn, WT_out, hidden, h1,
                                                     nullptr, nullptr, 0, nullptr, nullptr,
                                                     NTOK, DMODEL, DINNER);
  // 12. h2 = rmsnorm(h1) -> bf16
  rms_kernel<<<NTOK, 256, 0, stream>>>(h1, norm2_w, h2, DMODEL);
  // 12.5 convert gate weight (zbuf dead)
  wconv_kernel<<<dim3(88, 32), 256, 0, stream>>>(gate_w, WT_gate, DMODEL, INTER_);
  // 13. g = h2 @ gate_w -> gbuf (bf16)
  gemm3_kernel<<<dim3(22, 32), 512, dynLDS, stream>>>(h2, WT_gate, nullptr, nullptr,
                                                      gbuf, nullptr, INTER_, nullptr, nullptr,
                                                      NTOK, INTER_, DMODEL);
  // 13.5 convert up weight (xdt/ygn dead)
  wconv_kernel<<<dim3(88, 32), 256, 0, stream>>>(up_w, WT_up, DMODEL, INTER_);
  // 14. u = h2 @ up_w, fused: gbuf = silu(gbuf) * u
  gemm3_kernel<<<dim3(22, 32), 512, dynLDS, stream>>>(h2, WT_up, nullptr, nullptr,
                                                      gbuf, nullptr, INTER_, gbuf, nullptr,
                                                      NTOK, INTER_, DMODEL);
  // 14.5 convert down weight (h2 dead)
  wconv_kernel<<<dim3(32, 88), 256, 0, stream>>>(down_w, WT_down, INTER_, DMODEL);
  // 15. out = h1 + (g*u) @ down_w  (in place on d_out); grid 256 blocks = 1/CU exact
  gemm3_kernel<<<dim3(8, 32), 512, dynLDS, stream>>>(gbuf, WT_down, h1, outp,
                                                     nullptr, nullptr, 0, nullptr, nullptr,
                                                     NTOK, DMODEL, INTER_);
}

// Round 7
// 1087.523 us; speedup vs baseline: 1.2558x; 1.0229x over previous
//
#include <hip/hip_runtime.h>

#define LTOT 2048
#define BATCH 2
#define NTOK 4096
#define DMODEL 2048
#define DSTATE 128
#define NH 64
#define HD 64
#define DINNER 4096
#define CONVD 4352
#define XDTC 4416
#define INP 8512
#define INTER_ 5632
#define CHUNK_ 128
#define NCH 16
#define EPSF 1e-6f

typedef __bf16 bf16x8 __attribute__((ext_vector_type(8)));
typedef float f32x4 __attribute__((ext_vector_type(4)));
typedef unsigned short u16x4 __attribute__((ext_vector_type(4)));
typedef unsigned short u16x8 __attribute__((ext_vector_type(8)));

__device__ __forceinline__ unsigned short f2b(float f){
  unsigned int u = __builtin_bit_cast(unsigned int, f);
  u += 0x7fffu + ((u >> 16) & 1u);
  return (unsigned short)(u >> 16);
}
__device__ __forceinline__ float b2f(unsigned short h){
  return __builtin_bit_cast(float, ((unsigned int)h) << 16);
}
__device__ __forceinline__ f32x4 mfma16(bf16x8 a, bf16x8 b, f32x4 c){
  return __builtin_amdgcn_mfma_f32_16x16x32_bf16(a, b, c, 0, 0, 0);
}
// async global->LDS, 16B per lane, wave-uniform LDS base + lane*16
typedef const __attribute__((address_space(1))) void* gas_t;
typedef __attribute__((address_space(3))) void* las_t;
__device__ __forceinline__ void gload16(const void* g, void* l){
  __builtin_amdgcn_global_load_lds((gas_t)g, (las_t)l, 16, 0, 0);
}

// ---------------- weight convert: fp32 W[K][N] -> bf16 WT[Npad][K], zero rows n>=N ----------------
__global__ __launch_bounds__(256) void wconv_kernel(const float* __restrict__ W,
                                                    unsigned short* __restrict__ WT,
                                                    int K, int N)
{
  __shared__ unsigned short t[64][72];
  int n0 = blockIdx.x * 64, k0 = blockIdx.y * 64;
  int tid = threadIdx.x;
  int kl = tid >> 4, nl4 = (tid & 15) * 4;
  #pragma unroll
  for (int it = 0; it < 4; it++){
    int kk = kl + it * 16;
    float4 v = make_float4(0.f, 0.f, 0.f, 0.f);
    if (n0 < N) v = *(const float4*)&W[(size_t)(k0 + kk) * N + n0 + nl4];
    t[nl4 + 0][kk] = f2b(v.x);
    t[nl4 + 1][kk] = f2b(v.y);
    t[nl4 + 2][kk] = f2b(v.z);
    t[nl4 + 3][kk] = f2b(v.w);
  }
  __syncthreads();
  int nr = tid >> 3, k8 = (tid & 7) * 8;
  #pragma unroll
  for (int it = 0; it < 2; it++){
    int nn = nr + it * 32;
    *(u16x8*)&WT[(size_t)(n0 + nn) * K + k0 + k8] = *(const u16x8*)&t[nn][k8];
  }
}

// ---------------- RMSNorm: fp32 in -> bf16 out ----------------
__global__ __launch_bounds__(256) void rms_kernel(const float* __restrict__ x,
                                                  const float* __restrict__ w,
                                                  unsigned short* __restrict__ out, int width)
{
  int row = blockIdx.x, tid = threadIdx.x;
  const float* xr = x + (size_t)row * width;
  unsigned short* orow = out + (size_t)row * width;
  int nv = width >> 2;
  float ss = 0.f;
  for (int i = tid; i < nv; i += 256){
    float4 v = ((const float4*)xr)[i];
    ss += v.x*v.x + v.y*v.y + v.z*v.z + v.w*v.w;
  }
  #pragma unroll
  for (int off = 32; off > 0; off >>= 1) ss += __shfl_down(ss, off, 64);
  __shared__ float red[4];
  if ((tid & 63) == 0) red[tid >> 6] = ss;
  __syncthreads();
  float tot = red[0] + red[1] + red[2] + red[3];
  float scale = rsqrtf(tot / (float)width + EPSF);
  for (int i = tid; i < nv; i += 256){
    float4 v = ((const float4*)xr)[i];
    float4 wv = ((const float4*)w)[i];
    u16x4 o = { f2b(v.x * scale * wv.x), f2b(v.y * scale * wv.y),
                f2b(v.z * scale * wv.z), f2b(v.w * scale * wv.w) };
    ((u16x4*)orow)[i] = o;
  }
}

// ---------------- Gated RMSNorm: y fp32, z bf16 -> out bf16 ----------------
__global__ __launch_bounds__(256) void rms_gated_kernel(const float* __restrict__ y,
                                                        const unsigned short* __restrict__ z,
                                                        const float* __restrict__ w,
                                                        unsigned short* __restrict__ out)
{
  int row = blockIdx.x, tid = threadIdx.x;
  const float* yr = y + (size_t)row * DINNER;
  const unsigned short* zr = z + (size_t)row * DINNER;
  unsigned short* orow = out + (size_t)row * DINNER;
  float g[16];
  float ss = 0.f;
  #pragma unroll
  for (int ii = 0; ii < 4; ii++){
    int i = tid + ii * 256;
    float4 yv = ((const float4*)yr)[i];
    u16x4 zv = ((const u16x4*)zr)[i];
    #pragma unroll
    for (int e = 0; e < 4; e++){
      float zf = b2f(zv[e]);
      float yf = (&yv.x)[e];
      float gg = yf * (zf / (1.f + expf(-zf)));
      g[ii * 4 + e] = gg;
      ss += gg * gg;
    }
  }
  #pragma unroll
  for (int off = 32; off > 0; off >>= 1) ss += __shfl_down(ss, off, 64);
  __shared__ float red[4];
  if ((tid & 63) == 0) red[tid >> 6] = ss;
  __syncthreads();
  float tot = red[0] + red[1] + red[2] + red[3];
  float scale = rsqrtf(tot / (float)DINNER + EPSF);
  #pragma unroll
  for (int ii = 0; ii < 4; ii++){
    int i = tid + ii * 256;
    float4 wv = ((const float4*)w)[i];
    u16x4 o;
    #pragma unroll
    for (int e = 0; e < 4; e++) o[e] = f2b(g[ii * 4 + e] * scale * (&wv.x)[e]);
    ((u16x4*)orow)[i] = o;
  }
}

// ---------------- GEMM3: 128(M)x256(N) tile, BK=32, 8 waves, 3-buffer counted-vmcnt pipeline ----
// C = A(bf16,[M][K]) * BT(bf16,[Npad][K])^T. Dynamic LDS 72KB = 3 bufs x (A 8KB + B 16KB)
// -> 2 blocks/CU (16 waves): out-of-phase blocks overlap ds_read/stage with MFMA (m114).
// 2-tile-deep prefetch, 3 loads/thread/tile, per-tile wait = vmcnt(3) — never 0 mid-loop (T4).
// Buffer rows are 64B: swizzle oct' = oct ^ (row&3) (conflict-free b128 reads); staging source
// pre-swizzled to match (rule #21). XCD-aware bijective block swizzle (T1); setprio (T5).
__global__ __launch_bounds__(512, 2) void gemm3_kernel(const unsigned short* __restrict__ A,
                                                       const unsigned short* __restrict__ BT,
                                                       const float* __restrict__ addsrc,
                                                       float* __restrict__ Cf,
                                                       unsigned short* __restrict__ Cb,
                                                       unsigned short* __restrict__ Cb2, int splitN,
                                                       const unsigned short* __restrict__ gate,
                                                       float* __restrict__ dtraw,
                                                       int M, int N, int K)
{
  extern __shared__ unsigned short lds[];    // 36864 u16 = 72KB; buf i at i*12288 (A 4096, B 8192 u16)
  int tid = threadIdx.x, lane = tid & 63, w = tid >> 6;
  int wm = w >> 2, wn = w & 3;               // wave grid 2(M) x 4(N); wave block 64x64
  int bid = blockIdx.x + blockIdx.y * gridDim.x;
  int nwg = gridDim.x * gridDim.y;
  int q8 = nwg >> 3, r8 = nwg & 7;
  int xcd = bid & 7, boff = bid >> 3;
  int wgid = (xcd < r8 ? xcd * (q8 + 1) : r8 * (q8 + 1) + (xcd - r8) * q8) + boff;
  int bn = (wgid % gridDim.x) * 256;
  int bm = (wgid / gridDim.x) * 128;

  int soct8 = ((lane & 3) ^ ((lane >> 2) & 3)) << 3;   // staging source k-offset (pre-swizzled)
  int prow_l = (lane >> 2);                            // row-within-128 contribution of lane
  int ko = (((lane >> 4) ^ (lane & 3)) << 3);          // read-side swizzled k-offset
  int rsel = (lane & 15) * 32 + ko;

  f32x4 acc[4][4] = {};
  int NT = K >> 5;

  // stage K-tile kt into buffer bsel: 3 gloads/thread (j=0: A rows 0-127; j=1/2: B rows 0-255)
  #define STAGE(kt, bsel)                                                              \
    {                                                                                  \
      unsigned short* bb_ = &lds[(bsel) * 12288];                                      \
      size_t k0_ = (size_t)(kt) << 5;                                                  \
      gload16(&A [(size_t)(bm +       w * 16 + prow_l) * K + k0_ + soct8], &bb_[w * 512]);            \
      gload16(&BT[(size_t)(bn +       w * 16 + prow_l) * K + k0_ + soct8], &bb_[4096 + w * 512]);     \
      gload16(&BT[(size_t)(bn + 128 + w * 16 + prow_l) * K + k0_ + soct8], &bb_[8192 + w * 512]);     \
    }

  // prologue: stage tiles 0,1 (6 loads); wait tile 0 (vmcnt(3): tile 1's 3 still in flight)
  STAGE(0, 0)
  STAGE(1, 1)
  asm volatile("s_waitcnt vmcnt(3)" ::: "memory");
  __builtin_amdgcn_s_barrier();
  asm volatile("" ::: "memory");

  for (int t = 0; t < NT; ++t){
    const unsigned short* bufc = &lds[(t % 3) * 12288];
    bf16x8 afr[4], bfr[4];
    #pragma unroll
    for (int i = 0; i < 4; ++i)
      afr[i] = *(const bf16x8*)&bufc[(wm * 64 + i * 16) * 32 + rsel];
    #pragma unroll
    for (int c = 0; c < 4; ++c)
      bfr[c] = *(const bf16x8*)&bufc[4096 + (wn * 64 + c * 16) * 32 + rsel];
    // stage tile t+2 into buf[(t+2)%3] (its last reader was iter t-1, barrier-separated)
    if (t + 2 < NT) STAGE(t + 2, (t + 2) % 3)
    asm volatile("" ::: "memory");
    __builtin_amdgcn_s_barrier();
    asm volatile("s_waitcnt lgkmcnt(0)" ::: "memory");
    __builtin_amdgcn_s_setprio(1);
    #pragma unroll
    for (int i = 0; i < 4; ++i)
      #pragma unroll
      for (int c = 0; c < 4; ++c)
        acc[i][c] = mfma16(afr[i], bfr[c], acc[i][c]);
    __builtin_amdgcn_s_setprio(0);
    if (t + 2 < NT)      asm volatile("s_waitcnt vmcnt(3)" ::: "memory");  // t+1 landed
    else if (t + 1 < NT) asm volatile("s_waitcnt vmcnt(0)" ::: "memory");  // final drain
    asm volatile("" ::: "memory");
    __builtin_amdgcn_s_barrier();
    asm volatile("" ::: "memory");
  }
  #undef STAGE

  // epilogue (no LDS use)
  int r0 = bm + wm * 64 + ((lane >> 4) << 2);
  int c0 = bn + wn * 64 + (lane & 15);
  #pragma unroll
  for (int i = 0; i < 4; ++i){
    #pragma unroll
    for (int j = 0; j < 4; ++j){
      int cc = c0 + j * 16;
      if (cc < N){
        #pragma unroll
        for (int e = 0; e < 4; ++e){
          int rr = r0 + i * 16 + e;
          float v = acc[i][j][e];
          if (Cf){
            size_t idx = (size_t)rr * N + cc;
            if (addsrc) v += addsrc[idx];
            Cf[idx] = v;
          } else if (cc < splitN){
            size_t idx = (size_t)rr * splitN + cc;
            float vv = v;
            if (gate){ float gg = b2f(gate[idx]); vv = gg / (1.f + expf(-gg)) * v; }
            Cb[idx] = f2b(vv);
          } else {
            Cb2[(size_t)rr * (N - splitN) + (cc - splitN)] = f2b(v);
            if (dtraw && cc >= N - NH) dtraw[(size_t)rr * NH + (cc - (N - NH))] = v;
          }
        }
      }
    }
  }
}

// ---------------- dt = softplus(dtraw + dt_bias), fp32 path ----------------
__global__ __launch_bounds__(256) void dt_kernel(const float* __restrict__ dtraw,
                                                 const float* __restrict__ dt_bias,
                                                 float* __restrict__ dtb)
{
  int idx = blockIdx.x * 256 + threadIdx.x;
  float raw = dtraw[idx] + dt_bias[idx & 63];
  dtb[idx] = (raw > 20.f) ? raw : log1pf(expf(raw));
}

// ---------------- per (b,h,c) inclusive cumsum of dA = dt*A within chunk ----------------
__global__ __launch_bounds__(64) void acum_kernel(const float* __restrict__ dtb,
                                                  const float* __restrict__ A_log,
                                                  float* __restrict__ acum)
{
  int bid = blockIdx.x;          // (b*NH + h)*NCH + c
  int c = bid & 15;
  int hh = (bid >> 4) & 63;
  int b = bid >> 10;
  int lane = threadIdx.x;
  float Av = -expf(A_log[hh]);
  int rowbase = b * LTOT + c * CHUNK_;
  float v0 = dtb[(size_t)(rowbase + 2 * lane) * NH + hh] * Av;
  float v1 = dtb[(size_t)(rowbase + 2 * lane + 1) * NH + hh] * Av;
  float s = v0 + v1;
  #pragma unroll
  for (int d = 1; d < 64; d <<= 1){
    float t = __shfl_up(s, d, 64);
    if (lane >= d) s += t;
  }
  float excl = s - (v0 + v1);
  float* dst = acum + ((size_t)(b * NH + hh)) * LTOT + c * CHUNK_;
  dst[2 * lane]     = excl + v0;
  dst[2 * lane + 1] = excl + v0 + v1;
}

// ---------------- depthwise causal conv (width 4) + bias + SiLU, bf16 in/out ----------------
__global__ __launch_bounds__(256) void conv_kernel(const unsigned short* __restrict__ xdt,
                                                   const float* __restrict__ cw,
                                                   const float* __restrict__ cb,
                                                   unsigned short* __restrict__ xbc)
{
  int ch = blockIdx.x * 256 + threadIdx.x;   // 17*256 = 4352 = CONVD exactly
  int l = blockIdx.y, b = blockIdx.z;
  float acc = cb[ch];
  #pragma unroll
  for (int j = 0; j < 4; j++){
    int ls = l + j - 3;
    if (ls >= 0) acc += b2f(xdt[((size_t)(b * LTOT + ls)) * XDTC + ch]) * cw[ch * 4 + j];
  }
  acc = acc / (1.f + expf(-acc));
  xbc[((size_t)(b * LTOT + l)) * CONVD + ch] = f2b(acc);
}

// ---------------- SSD part 1: S' = (C·B^T)⊙L, Y_diag = S'·(x·dt)^T ----------------
__global__ __launch_bounds__(256) void ssd_sy_kernel(const unsigned short* __restrict__ xbc,
                                                     const float* __restrict__ dtb,
                                                     const float* __restrict__ acum,
                                                     float* __restrict__ y)
{
  int hh = blockIdx.x;
  int c = blockIdx.y >> 1;
  int half = blockIdx.y & 1;
  int b = blockIdx.z;
  __shared__ unsigned short Cs[64][136];    // C rows (l0..l0+63), later S'
  __shared__ unsigned short Bs[128][136];   // B rows (all s), later XT (rows 0..63 = p)
  __shared__ float ac[128];
  int tid = threadIdx.x, lane = tid & 63, w = tid >> 6;
  int l0 = half * 64;
  size_t rowbase = (size_t)b * LTOT + c * CHUNK_;
  if (tid < 128) ac[tid] = acum[((size_t)(b * NH + hh)) * LTOT + c * CHUNK_ + tid];
  #pragma unroll
  for (int p = 0; p < 8; p++){
    int lr = p * 8 + (tid >> 5);
    int n4 = (tid & 31) * 4;
    *(u16x4*)&Cs[lr][n4] =
      *(const u16x4*)&xbc[(rowbase + l0 + lr) * CONVD + DINNER + DSTATE + n4];
  }
  #pragma unroll
  for (int p = 0; p < 16; p++){
    int s = p * 8 + (tid >> 5);
    int n4 = (tid & 31) * 4;
    *(u16x4*)&Bs[s][n4] = *(const u16x4*)&xbc[(rowbase + s) * CONVD + DINNER + n4];
  }
  __syncthreads();
  f32x4 accS[8] = {};
  #pragma unroll
  for (int kk = 0; kk < 4; kk++){
    bf16x8 a = *(const bf16x8*)&Cs[w * 16 + (lane & 15)][kk * 32 + (lane >> 4) * 8];
    #pragma unroll
    for (int fc = 0; fc < 8; fc++){
      bf16x8 bb = *(const bf16x8*)&Bs[fc * 16 + (lane & 15)][kk * 32 + (lane >> 4) * 8];
      accS[fc] = mfma16(a, bb, accS[fc]);
    }
  }
  __syncthreads();
  // S' into Cs
  {
    int lr = w * 16 + ((lane >> 4) << 2);
    #pragma unroll
    for (int fc = 0; fc < 8; fc++){
      int s = fc * 16 + (lane & 15);
      #pragma unroll
      for (int j = 0; j < 4; j++){
        int l = l0 + lr + j;
        float v = (s <= l) ? accS[fc][j] * expf(ac[l] - ac[s]) : 0.f;
        Cs[lr + j][s] = f2b(v);
      }
    }
  }
  // XT = (x*dt)^T into Bs rows 0..63
  #pragma unroll
  for (int p = 0; p < 8; p++){
    int lr = p * 16 + (tid >> 4);
    int p4 = (tid & 15) * 4;
    float dtl = dtb[(rowbase + lr) * NH + hh];
    u16x4 v = *(const u16x4*)&xbc[(rowbase + lr) * CONVD + hh * HD + p4];
    Bs[p4 + 0][lr] = f2b(b2f(v[0]) * dtl);
    Bs[p4 + 1][lr] = f2b(b2f(v[1]) * dtl);
    Bs[p4 + 2][lr] = f2b(b2f(v[2]) * dtl);
    Bs[p4 + 3][lr] = f2b(b2f(v[3]) * dtl);
  }
  __syncthreads();
  f32x4 accY[4] = {};
  #pragma unroll
  for (int kk = 0; kk < 4; kk++){
    bf16x8 a = *(const bf16x8*)&Cs[w * 16 + (lane & 15)][kk * 32 + (lane >> 4) * 8];
    #pragma unroll
    for (int fc = 0; fc < 4; fc++){
      bf16x8 bb = *(const bf16x8*)&Bs[fc * 16 + (lane & 15)][kk * 32 + (lane >> 4) * 8];
      accY[fc] = mfma16(a, bb, accY[fc]);
    }
  }
  {
    int lr = w * 16 + ((lane >> 4) << 2);
    #pragma unroll
    for (int fc = 0; fc < 4; fc++){
      int p = fc * 16 + (lane & 15);
      #pragma unroll
      for (int j = 0; j < 4; j++){
        y[(rowbase + l0 + lr + j) * DINNER + hh * HD + p] = accY[fc][j];
      }
    }
  }
}

// ---------------- SSD part 2: states[p][n] = sum_l (x*dt*decay)[l][p] * B[l][n] ----------------
__global__ __launch_bounds__(256) void ssd_states_kernel(const unsigned short* __restrict__ xbc,
                                                         const float* __restrict__ dtb,
                                                         const float* __restrict__ acum,
                                                         unsigned short* __restrict__ states)
{
  int hh = blockIdx.x, c = blockIdx.y, b = blockIdx.z;
  __shared__ unsigned short BsT[128][136];  // [n][l]
  __shared__ unsigned short XT[64][136];    // [p][l]
  __shared__ float ac[128];
  int tid = threadIdx.x, lane = tid & 63, w = tid >> 6;
  size_t rowbase = (size_t)b * LTOT + c * CHUNK_;
  if (tid < 128) ac[tid] = acum[((size_t)(b * NH + hh)) * LTOT + c * CHUNK_ + tid];
  #pragma unroll
  for (int p = 0; p < 16; p++){
    int l = p * 8 + (tid >> 5);
    int n4 = (tid & 31) * 4;
    u16x4 v = *(const u16x4*)&xbc[(rowbase + l) * CONVD + DINNER + n4];
    BsT[n4 + 0][l] = v[0];
    BsT[n4 + 1][l] = v[1];
    BsT[n4 + 2][l] = v[2];
    BsT[n4 + 3][l] = v[3];
  }
  #pragma unroll
  for (int p = 0; p < 8; p++){
    int l = p * 16 + (tid >> 4);
    int p4 = (tid & 15) * 4;
    float dtl = dtb[(rowbase + l) * NH + hh];
    u16x4 v = *(const u16x4*)&xbc[(rowbase + l) * CONVD + hh * HD + p4];
    XT[p4 + 0][l] = f2b(b2f(v[0]) * dtl);
    XT[p4 + 1][l] = f2b(b2f(v[1]) * dtl);
    XT[p4 + 2][l] = f2b(b2f(v[2]) * dtl);
    XT[p4 + 3][l] = f2b(b2f(v[3]) * dtl);
  }
  __syncthreads();
  float aclast = ac[127];
  f32x4 accP[8] = {};
  #pragma unroll
  for (int kk = 0; kk < 4; kk++){
    int kbase = kk * 32 + (lane >> 4) * 8;
    union { u16x4 q[2]; unsigned short u[8]; bf16x8 v; } rw, ot;
    rw.q[0] = *(const u16x4*)&XT[w * 16 + (lane & 15)][kbase];
    rw.q[1] = *(const u16x4*)&XT[w * 16 + (lane & 15)][kbase + 4];
    #pragma unroll
    for (int e = 0; e < 8; e++){
      ot.u[e] = f2b(b2f(rw.u[e]) * expf(aclast - ac[kbase + e]));
    }
    #pragma unroll
    for (int fc = 0; fc < 8; fc++){
      bf16x8 bb = *(const bf16x8*)&BsT[fc * 16 + (lane & 15)][kbase];
      accP[fc] = mfma16(ot.v, bb, accP[fc]);
    }
  }
  size_t sbase = ((size_t)((b * NCH + c) * NH + hh)) * HD * DSTATE;
  int p0 = w * 16 + ((lane >> 4) << 2);
  #pragma unroll
  for (int fc = 0; fc < 8; fc++){
    int n = fc * 16 + (lane & 15);
    #pragma unroll
    for (int j = 0; j < 4; j++){
      states[sbase + (size_t)(p0 + j) * DSTATE + n] = f2b(accP[fc][j]);
    }
  }
}

// ---------------- SSD part 3: inter-chunk scan, in-place states -> prev ----------------
__global__ __launch_bounds__(256) void scan_kernel(unsigned short* __restrict__ states,
                                                   const float* __restrict__ acum)
{
  int bh = blockIdx.x;           // b*NH + h
  int b = bh >> 6, hh = bh & 63;
  int t = threadIdx.x;
  float run[32];
  #pragma unroll
  for (int j = 0; j < 32; j++) run[j] = 0.f;
  for (int c = 0; c < NCH; c++){
    float alast = acum[(size_t)bh * LTOT + c * CHUNK_ + 127];
    float dec = expf(alast);
    size_t base = ((size_t)((b * NCH + c) * NH + hh)) * (HD * DSTATE);
    #pragma unroll
    for (int j = 0; j < 32; j++){
      size_t idx = base + (size_t)j * 256 + t;
      float sc = b2f(states[idx]);
      states[idx] = f2b(run[j]);
      run[j] = run[j] * dec + sc;
    }
  }
}

// ---------------- SSD part 4: Y_off = decay[l] * C·prev^T, plus D*x, added into y ----------------
__global__ __launch_bounds__(256) void ssd3_kernel(const unsigned short* __restrict__ xbc,
                                                   const unsigned short* __restrict__ states,
                                                   const float* __restrict__ acum,
                                                   const float* __restrict__ Dp,
                                                   float* __restrict__ y)
{
  int hh = blockIdx.x, c = blockIdx.y, b = blockIdx.z;
  __shared__ unsigned short Cs[128][136];
  __shared__ unsigned short Ps[64][136];   // prev [p][n]
  __shared__ float ac[128];
  int tid = threadIdx.x, lane = tid & 63, w = tid >> 6;
  size_t rowbase = (size_t)b * LTOT + c * CHUNK_;
  if (tid < 128) ac[tid] = acum[((size_t)(b * NH + hh)) * LTOT + c * CHUNK_ + tid];
  #pragma unroll
  for (int p = 0; p < 16; p++){
    int l = p * 8 + (tid >> 5);
    int n4 = (tid & 31) * 4;
    *(u16x4*)&Cs[l][n4] =
      *(const u16x4*)&xbc[(rowbase + l) * CONVD + DINNER + DSTATE + n4];
  }
  size_t sbase = ((size_t)((b * NCH + c) * NH + hh)) * (HD * DSTATE);
  #pragma unroll
  for (int p = 0; p < 8; p++){
    int pp = p * 8 + (tid >> 5);
    int n4 = (tid & 31) * 4;
    *(u16x4*)&Ps[pp][n4] = *(const u16x4*)&states[sbase + (size_t)pp * DSTATE + n4];
  }
  __syncthreads();
  f32x4 acc[2][4] = {};
  #pragma unroll
  for (int kk = 0; kk < 4; kk++){
    bf16x8 a0 = *(const bf16x8*)&Cs[w * 32 + (lane & 15)][kk * 32 + (lane >> 4) * 8];
    bf16x8 a1 = *(const bf16x8*)&Cs[w * 32 + 16 + (lane & 15)][kk * 32 + (lane >> 4) * 8];
    #pragma unroll
    for (int fc = 0; fc < 4; fc++){
      bf16x8 bb = *(const bf16x8*)&Ps[fc * 16 + (lane & 15)][kk * 32 + (lane >> 4) * 8];
      acc[0][fc] = mfma16(a0, bb, acc[0][fc]);
      acc[1][fc] = mfma16(a1, bb, acc[1][fc]);
    }
  }
  float dpar = Dp[hh];
  #pragma unroll
  for (int fr = 0; fr < 2; fr++){
    int lr = w * 32 + fr * 16 + ((lane >> 4) << 2);
    #pragma unroll
    for (int fc = 0; fc < 4; fc++){
      int p = fc * 16 + (lane & 15);
      #pragma unroll
      for (int j = 0; j < 4; j++){
        int l = lr + j;
        size_t yi = (rowbase + l) * DINNER + hh * HD + p;
        float xsv = b2f(xbc[(rowbase + l) * CONVD + hh * HD + p]);
        y[yi] += acc[fr][fc][j] * expf(ac[l]) + dpar * xsv;
      }
    }
  }
}

extern "C" void kernel_launch(void* const* d_in, const int* in_sizes, int n_in,
                              void* d_out, int out_size, void* d_ws, size_t ws_size,
                              hipStream_t stream)
{
  (void)in_sizes; (void)n_in; (void)out_size; (void)ws_size;
  const float* hidden    = (const float*)d_in[0];
  const float* norm1_w   = (const float*)d_in[1];
  const float* in_proj_w = (const float*)d_in[2];
  const float* conv_w    = (const float*)d_in[3];
  const float* conv_b    = (const float*)d_in[4];
  const float* dt_bias   = (const float*)d_in[5];
  const float* A_log     = (const float*)d_in[6];
  const float* D_param   = (const float*)d_in[7];
  const float* mixer_w   = (const float*)d_in[8];
  const float* out_proj_w= (const float*)d_in[9];
  const float* norm2_w   = (const float*)d_in[10];
  const float* gate_w    = (const float*)d_in[11];
  const float* up_w      = (const float*)d_in[12];
  const float* down_w    = (const float*)d_in[13];

  char* ws = (char*)d_ws;
  // Workspace layout (total 175,636,480 bytes), live-range-verified aliases.
  unsigned short* zbuf    = (unsigned short*)(ws);                  // bf16 4096x4096 [k2..k10]
  unsigned short* WT_gate = (unsigned short*)(ws);                  // bf16 5632x2048 [k12.5..k13] (zbuf dead)
  unsigned short* xdt     = (unsigned short*)(ws + 33554432ull);    // bf16 4096x4416 [k2..k5]
  unsigned short* states  = (unsigned short*)(ws + 33554432ull);    // bf16 16.7M el  [k7..k9]
  unsigned short* ygn     = (unsigned short*)(ws + 33554432ull);    // bf16 4096x4096 [k10..k11]
  unsigned short* WT_up   = (unsigned short*)(ws + 33554432ull);    // bf16 5632x2048 [k13.5..k14]
  unsigned short* xbc     = (unsigned short*)(ws + 69730304ull);    // bf16 4096x4352 [k5..k9]
  unsigned short* WT_out  = (unsigned short*)(ws + 69730304ull);    // bf16 2048x4096 [k10.5..k11]
  unsigned short* h2      = (unsigned short*)(ws + 69730304ull);    // bf16 4096x2048 [k12..k14]
  unsigned short* WT_down = (unsigned short*)(ws + 69730304ull);    // bf16 2048x5632 [k14.5..k15]
  float* dtraw            = (float*)(ws + 105381888ull);            // f32 4096x64 [k2..k3]
  float* dtb              = (float*)(ws + 106430464ull);            // f32 4096x64 [k3..k9]
  float* acum             = (float*)(ws + 107479040ull);            // f32 128x2048 [k4..k9]
  float* ybuf             = (float*)(ws + 108527616ull);            // f32 4096x4096 [k6..k10]
  unsigned short* hbuf    = (unsigned short*)(ws + 108527616ull);   // bf16 4096x2048 [k1..k2]
  unsigned short* gbuf    = (unsigned short*)(ws + 108527616ull);   // bf16 4096x5632 [k13..k16]
  unsigned short* WT_in   = (unsigned short*)(ws + 125304832ull);   // bf16 8704x2048 [k0..k2]
  float* h1               = (float*)d_out;                          // f32 4096x2048 [k11..k16]
  float* outp             = (float*)d_out;

  const int dynLDS = 73728;   // 3 x 24KB -> 2 blocks/CU
  hipFuncSetAttribute((const void*)gemm3_kernel,
                      hipFuncAttributeMaxDynamicSharedMemorySize, dynLDS);

  // 0. convert in_proj weight -> bf16 [8704][2048] (rows >= 8512 zeroed; 8704 = 34*256)
  wconv_kernel<<<dim3(136, 32), 256, 0, stream>>>(in_proj_w, WT_in, DMODEL, INP);
  // 1. h = rmsnorm(hidden) -> bf16
  rms_kernel<<<NTOK, 256, 0, stream>>>(hidden, norm1_w, hbuf, DMODEL);
  // 2. zxbcdt = h @ in_proj: cols<4096 -> zbuf, cols>=4096 -> xdt; dt cols fp32 -> dtraw
  gemm3_kernel<<<dim3(34, 32), 512, dynLDS, stream>>>(hbuf, WT_in, nullptr, nullptr,
                                                      zbuf, xdt, DINNER, nullptr, dtraw,
                                                      NTOK, INP, DMODEL);
  // 3. dt = softplus(dtraw + bias)
  dt_kernel<<<NTOK * NH / 256, 256, 0, stream>>>(dtraw, dt_bias, dtb);
  // 4. per-chunk cumsum of dt*A
  acum_kernel<<<BATCH * NH * NCH, 64, 0, stream>>>(dtb, A_log, acum);
  // 5. conv + silu
  conv_kernel<<<dim3(CONVD / 256, LTOT, BATCH), 256, 0, stream>>>(xdt, conv_w, conv_b, xbc);
  // 6. SSD intra-chunk: Y_diag
  ssd_sy_kernel<<<dim3(NH, NCH * 2, BATCH), 256, 0, stream>>>(xbc, dtb, acum, ybuf);
  // 7. SSD per-chunk states
  ssd_states_kernel<<<dim3(NH, NCH, BATCH), 256, 0, stream>>>(xbc, dtb, acum, states);
  // 8. inter-chunk scan (in-place -> prev)
  scan_kernel<<<BATCH * NH, 256, 0, stream>>>(states, acum);
  // 9. SSD off-diagonal + D*x
  ssd3_kernel<<<dim3(NH, NCH, BATCH), 256, 0, stream>>>(xbc, states, acum, D_param, ybuf);
  // 10. gated rmsnorm: ygn = rmsnorm(y * silu(z))
  rms_gated_kernel<<<NTOK, 256, 0, stream>>>(ybuf, zbuf, mixer_w, ygn);
  // 10.5 convert out_proj weight (xbc region dead)
  wconv_kernel<<<dim3(32, 64), 256, 0, stream>>>(out_proj_w, WT_out, DINNER, DMODEL);
  // 11. h1 = hidden + ygn @ out_proj  (into d_out); grid 8x32 = 256 blocks
  gemm3_kernel<<<dim3(8, 32), 512, dynLDS, stream>>>(ygn, WT_out, hidden, h1,
                                                     nullptr, nullptr, 0, nullptr, nullptr,
                                                     NTOK, DMODEL, DINNER);
  // 12. h2 = rmsnorm(h1) -> bf16
  rms_kernel<<<NTOK, 256, 0, stream>>>(h1, norm2_w, h2, DMODEL);
  // 12.5 convert gate weight (zbuf dead)
  wconv_kernel<<<dim3(88, 32), 256, 0, stream>>>(gate_w, WT_gate, DMODEL, INTER_);
  // 13. g = h2 @ gate_w -> gbuf (bf16)
  gemm3_kernel<<<dim3(22, 32), 512, dynLDS, stream>>>(h2, WT_gate, nullptr, nullptr,
                                                      gbuf, nullptr, INTER_, nullptr, nullptr,
                                                      NTOK, INTER_, DMODEL);
  // 13.5 convert up weight (xdt/ygn dead)
  wconv_kernel<<<dim3(88, 32), 256, 0, stream>>>(up_w, WT_up, DMODEL, INTER_);
  // 14. u = h2 @ up_w, fused: gbuf = silu(gbuf) * u
  gemm3_kernel<<<dim3(22, 32), 512, dynLDS, stream>>>(h2, WT_up, nullptr, nullptr,
                                                      gbuf, nullptr, INTER_, gbuf, nullptr,
                                                      NTOK, INTER_, DMODEL);
  // 14.5 convert down weight (h2 dead)
  wconv_kernel<<<dim3(32, 88), 256, 0, stream>>>(down_w, WT_down, INTER_, DMODEL);
  // 15. out = h1 + (g*u) @ down_w  (in place on d_out); grid 256 blocks
  gemm3_kernel<<<dim3(8, 32), 512, dynLDS, stream>>>(gbuf, WT_down, h1, outp,
                                                     nullptr, nullptr, 0, nullptr, nullptr,
                                                     NTOK, DMODEL, INTER_);
}

// Round 8
// 1036.438 us; speedup vs baseline: 1.3177x; 1.0493x over previous
//
#include <hip/hip_runtime.h>

#define LTOT 2048
#define BATCH 2
#define NTOK 4096
#define DMODEL 2048
#define DSTATE 128
#define NH 64
#define HD 64
#define DINNER 4096
#define CONVD 4352
#define XDTC 4416
#define INP 8512
#define INTER_ 5632
#define CHUNK_ 128
#define NCH 16
#define EPSF 1e-6f

typedef __bf16 bf16x8 __attribute__((ext_vector_type(8)));
typedef float f32x4 __attribute__((ext_vector_type(4)));
typedef unsigned short u16x4 __attribute__((ext_vector_type(4)));
typedef unsigned short u16x8 __attribute__((ext_vector_type(8)));

__device__ __forceinline__ unsigned short f2b(float f){
  unsigned int u = __builtin_bit_cast(unsigned int, f);
  u += 0x7fffu + ((u >> 16) & 1u);
  return (unsigned short)(u >> 16);
}
__device__ __forceinline__ float b2f(unsigned short h){
  return __builtin_bit_cast(float, ((unsigned int)h) << 16);
}
__device__ __forceinline__ f32x4 mfma16(bf16x8 a, bf16x8 b, f32x4 c){
  return __builtin_amdgcn_mfma_f32_16x16x32_bf16(a, b, c, 0, 0, 0);
}
// async global->LDS, 16B per lane, wave-uniform LDS base + lane*16
typedef const __attribute__((address_space(1))) void* gas_t;
typedef __attribute__((address_space(3))) void* las_t;
__device__ __forceinline__ void gload16(const void* g, void* l){
  __builtin_amdgcn_global_load_lds((gas_t)g, (las_t)l, 16, 0, 0);
}

// ---------------- weight convert: fp32 W[K][N] -> bf16 WT[Npad][K], zero rows n>=N ----------------
__global__ __launch_bounds__(256) void wconv_kernel(const float* __restrict__ W,
                                                    unsigned short* __restrict__ WT,
                                                    int K, int N)
{
  __shared__ unsigned short t[64][72];
  int n0 = blockIdx.x * 64, k0 = blockIdx.y * 64;
  int tid = threadIdx.x;
  int kl = tid >> 4, nl4 = (tid & 15) * 4;
  #pragma unroll
  for (int it = 0; it < 4; it++){
    int kk = kl + it * 16;
    float4 v = make_float4(0.f, 0.f, 0.f, 0.f);
    if (n0 < N) v = *(const float4*)&W[(size_t)(k0 + kk) * N + n0 + nl4];
    t[nl4 + 0][kk] = f2b(v.x);
    t[nl4 + 1][kk] = f2b(v.y);
    t[nl4 + 2][kk] = f2b(v.z);
    t[nl4 + 3][kk] = f2b(v.w);
  }
  __syncthreads();
  int nr = tid >> 3, k8 = (tid & 7) * 8;
  #pragma unroll
  for (int it = 0; it < 2; it++){
    int nn = nr + it * 32;
    *(u16x8*)&WT[(size_t)(n0 + nn) * K + k0 + k8] = *(const u16x8*)&t[nn][k8];
  }
}

// ---------------- RMSNorm: fp32 in -> bf16 out ----------------
__global__ __launch_bounds__(256) void rms_kernel(const float* __restrict__ x,
                                                  const float* __restrict__ w,
                                                  unsigned short* __restrict__ out, int width)
{
  int row = blockIdx.x, tid = threadIdx.x;
  const float* xr = x + (size_t)row * width;
  unsigned short* orow = out + (size_t)row * width;
  int nv = width >> 2;
  float ss = 0.f;
  for (int i = tid; i < nv; i += 256){
    float4 v = ((const float4*)xr)[i];
    ss += v.x*v.x + v.y*v.y + v.z*v.z + v.w*v.w;
  }
  #pragma unroll
  for (int off = 32; off > 0; off >>= 1) ss += __shfl_down(ss, off, 64);
  __shared__ float red[4];
  if ((tid & 63) == 0) red[tid >> 6] = ss;
  __syncthreads();
  float tot = red[0] + red[1] + red[2] + red[3];
  float scale = rsqrtf(tot / (float)width + EPSF);
  for (int i = tid; i < nv; i += 256){
    float4 v = ((const float4*)xr)[i];
    float4 wv = ((const float4*)w)[i];
    u16x4 o = { f2b(v.x * scale * wv.x), f2b(v.y * scale * wv.y),
                f2b(v.z * scale * wv.z), f2b(v.w * scale * wv.w) };
    ((u16x4*)orow)[i] = o;
  }
}

// ---------------- Gated RMSNorm: y fp32, z bf16 -> out bf16 ----------------
__global__ __launch_bounds__(256) void rms_gated_kernel(const float* __restrict__ y,
                                                        const unsigned short* __restrict__ z,
                                                        const float* __restrict__ w,
                                                        unsigned short* __restrict__ out)
{
  int row = blockIdx.x, tid = threadIdx.x;
  const float* yr = y + (size_t)row * DINNER;
  const unsigned short* zr = z + (size_t)row * DINNER;
  unsigned short* orow = out + (size_t)row * DINNER;
  float g[16];
  float ss = 0.f;
  #pragma unroll
  for (int ii = 0; ii < 4; ii++){
    int i = tid + ii * 256;
    float4 yv = ((const float4*)yr)[i];
    u16x4 zv = ((const u16x4*)zr)[i];
    #pragma unroll
    for (int e = 0; e < 4; e++){
      float zf = b2f(zv[e]);
      float yf = (&yv.x)[e];
      float gg = yf * (zf / (1.f + expf(-zf)));
      g[ii * 4 + e] = gg;
      ss += gg * gg;
    }
  }
  #pragma unroll
  for (int off = 32; off > 0; off >>= 1) ss += __shfl_down(ss, off, 64);
  __shared__ float red[4];
  if ((tid & 63) == 0) red[tid >> 6] = ss;
  __syncthreads();
  float tot = red[0] + red[1] + red[2] + red[3];
  float scale = rsqrtf(tot / (float)DINNER + EPSF);
  #pragma unroll
  for (int ii = 0; ii < 4; ii++){
    int i = tid + ii * 256;
    float4 wv = ((const float4*)w)[i];
    u16x4 o;
    #pragma unroll
    for (int e = 0; e < 4; e++) o[e] = f2b(g[ii * 4 + e] * scale * (&wv.x)[e]);
    ((u16x4*)orow)[i] = o;
  }
}

// ---------------- GEMM3: 128(M)x256(N), BK=32, 8 waves, 3-buf counted-vmcnt, ONE barrier/tile ----
// Hazards (verified): reads of buf[t] published by prev iter's vmcnt+barrier; staging buf[t+2]
// safe because its last readers retired at their lgkmcnt(0) before the prev barrier.
__global__ __launch_bounds__(512, 2) void gemm3_kernel(const unsigned short* __restrict__ A,
                                                       const unsigned short* __restrict__ BT,
                                                       const float* __restrict__ addsrc,
                                                       float* __restrict__ Cf,
                                                       unsigned short* __restrict__ Cb,
                                                       unsigned short* __restrict__ Cb2, int splitN,
                                                       const unsigned short* __restrict__ gate,
                                                       float* __restrict__ dtraw,
                                                       int M, int N, int K)
{
  extern __shared__ unsigned short lds[];    // 36864 u16 = 72KB; buf i at i*12288 (A 4096, B 8192 u16)
  int tid = threadIdx.x, lane = tid & 63, w = tid >> 6;
  int wm = w >> 2, wn = w & 3;               // wave grid 2(M) x 4(N); wave block 64x64
  int bid = blockIdx.x + blockIdx.y * gridDim.x;
  int nwg = gridDim.x * gridDim.y;
  int q8 = nwg >> 3, r8 = nwg & 7;
  int xcd = bid & 7, boff = bid >> 3;
  int wgid = (xcd < r8 ? xcd * (q8 + 1) : r8 * (q8 + 1) + (xcd - r8) * q8) + boff;
  int bn = (wgid % gridDim.x) * 256;
  int bm = (wgid / gridDim.x) * 128;

  int soct8 = ((lane & 3) ^ ((lane >> 2) & 3)) << 3;   // staging source k-offset (pre-swizzled)
  int prow_l = (lane >> 2);
  int ko = (((lane >> 4) ^ (lane & 3)) << 3);          // read-side swizzled k-offset
  int rsel = (lane & 15) * 32 + ko;

  f32x4 acc[4][4] = {};
  int NT = K >> 5;

  #define STAGE(kt, bsel)                                                              \
    {                                                                                  \
      unsigned short* bb_ = &lds[(bsel) * 12288];                                      \
      size_t k0_ = (size_t)(kt) << 5;                                                  \
      gload16(&A [(size_t)(bm +       w * 16 + prow_l) * K + k0_ + soct8], &bb_[w * 512]);            \
      gload16(&BT[(size_t)(bn +       w * 16 + prow_l) * K + k0_ + soct8], &bb_[4096 + w * 512]);     \
      gload16(&BT[(size_t)(bn + 128 + w * 16 + prow_l) * K + k0_ + soct8], &bb_[8192 + w * 512]);     \
    }

  STAGE(0, 0)
  STAGE(1, 1)
  asm volatile("s_waitcnt vmcnt(3)" ::: "memory");
  __builtin_amdgcn_s_barrier();
  asm volatile("" ::: "memory");

  for (int t = 0; t < NT; ++t){
    const unsigned short* bufc = &lds[(t % 3) * 12288];
    bf16x8 afr[4], bfr[4];
    #pragma unroll
    for (int i = 0; i < 4; ++i)
      afr[i] = *(const bf16x8*)&bufc[(wm * 64 + i * 16) * 32 + rsel];
    #pragma unroll
    for (int c = 0; c < 4; ++c)
      bfr[c] = *(const bf16x8*)&bufc[4096 + (wn * 64 + c * 16) * 32 + rsel];
    if (t + 2 < NT) STAGE(t + 2, (t + 2) % 3)
    asm volatile("s_waitcnt lgkmcnt(0)" ::: "memory");
    __builtin_amdgcn_s_setprio(1);
    #pragma unroll
    for (int i = 0; i < 4; ++i)
      #pragma unroll
      for (int c = 0; c < 4; ++c)
        acc[i][c] = mfma16(afr[i], bfr[c], acc[i][c]);
    __builtin_amdgcn_s_setprio(0);
    if (t + 2 < NT)      asm volatile("s_waitcnt vmcnt(3)" ::: "memory");  // t+1 landed
    else if (t + 1 < NT) asm volatile("s_waitcnt vmcnt(0)" ::: "memory");  // final drain
    asm volatile("" ::: "memory");
    __builtin_amdgcn_s_barrier();
    asm volatile("" ::: "memory");
  }
  #undef STAGE

  int r0 = bm + wm * 64 + ((lane >> 4) << 2);
  int c0 = bn + wn * 64 + (lane & 15);
  #pragma unroll
  for (int i = 0; i < 4; ++i){
    #pragma unroll
    for (int j = 0; j < 4; ++j){
      int cc = c0 + j * 16;
      if (cc < N){
        #pragma unroll
        for (int e = 0; e < 4; ++e){
          int rr = r0 + i * 16 + e;
          float v = acc[i][j][e];
          if (Cf){
            size_t idx = (size_t)rr * N + cc;
            if (addsrc) v += addsrc[idx];
            Cf[idx] = v;
          } else if (cc < splitN){
            size_t idx = (size_t)rr * splitN + cc;
            float vv = v;
            if (gate){ float gg = b2f(gate[idx]); vv = gg / (1.f + expf(-gg)) * v; }
            Cb[idx] = f2b(vv);
          } else {
            Cb2[(size_t)rr * (N - splitN) + (cc - splitN)] = f2b(v);
            if (dtraw && cc >= N - NH) dtraw[(size_t)rr * NH + (cc - (N - NH))] = v;
          }
        }
      }
    }
  }
}

// ---------------- GEMM4: 128(M)x128(N), BK=32, 4 waves (2x2), 3x16KB bufs -> 3 blocks/CU -------
// For narrow-N GEMMs (out/down, N=2048): grid 512 blocks = full GPU + co-residency.
// Same single-barrier counted-vmcnt pipeline; 4 loads/thread/tile -> vmcnt(4).
__global__ __launch_bounds__(256, 3) void gemm4_kernel(const unsigned short* __restrict__ A,
                                                       const unsigned short* __restrict__ BT,
                                                       const float* __restrict__ addsrc,
                                                       float* __restrict__ Cf,
                                                       int M, int N, int K)
{
  extern __shared__ unsigned short lds[];    // 24576 u16 = 48KB; buf i at i*8192 (A 4096, B 4096)
  int tid = threadIdx.x, lane = tid & 63, w = tid >> 6;
  int wm = w >> 1, wn = w & 1;               // wave grid 2(M) x 2(N); wave block 64x64
  int bid = blockIdx.x + blockIdx.y * gridDim.x;
  int nwg = gridDim.x * gridDim.y;
  int q8 = nwg >> 3, r8 = nwg & 7;
  int xcd = bid & 7, boff = bid >> 3;
  int wgid = (xcd < r8 ? xcd * (q8 + 1) : r8 * (q8 + 1) + (xcd - r8) * q8) + boff;
  int bn = (wgid % gridDim.x) * 128;
  int bm = (wgid / gridDim.x) * 128;

  int soct8 = ((lane & 3) ^ ((lane >> 2) & 3)) << 3;
  int prow_l = (lane >> 2);
  int ko = (((lane >> 4) ^ (lane & 3)) << 3);
  int rsel = (lane & 15) * 32 + ko;

  f32x4 acc[4][4] = {};
  int NT = K >> 5;

  #define STAGE4(kt, bsel)                                                             \
    {                                                                                  \
      unsigned short* bb_ = &lds[(bsel) * 8192];                                       \
      size_t k0_ = (size_t)(kt) << 5;                                                  \
      gload16(&A [(size_t)(bm +      w * 16 + prow_l) * K + k0_ + soct8], &bb_[w * 512]);          \
      gload16(&A [(size_t)(bm + 64 + w * 16 + prow_l) * K + k0_ + soct8], &bb_[2048 + w * 512]);   \
      gload16(&BT[(size_t)(bn +      w * 16 + prow_l) * K + k0_ + soct8], &bb_[4096 + w * 512]);   \
      gload16(&BT[(size_t)(bn + 64 + w * 16 + prow_l) * K + k0_ + soct8], &bb_[6144 + w * 512]);   \
    }

  STAGE4(0, 0)
  STAGE4(1, 1)
  asm volatile("s_waitcnt vmcnt(4)" ::: "memory");
  __builtin_amdgcn_s_barrier();
  asm volatile("" ::: "memory");

  for (int t = 0; t < NT; ++t){
    const unsigned short* bufc = &lds[(t % 3) * 8192];
    bf16x8 afr[4], bfr[4];
    #pragma unroll
    for (int i = 0; i < 4; ++i)
      afr[i] = *(const bf16x8*)&bufc[(wm * 64 + i * 16) * 32 + rsel];
    #pragma unroll
    for (int c = 0; c < 4; ++c)
      bfr[c] = *(const bf16x8*)&bufc[4096 + (wn * 64 + c * 16) * 32 + rsel];
    if (t + 2 < NT) STAGE4(t + 2, (t + 2) % 3)
    asm volatile("s_waitcnt lgkmcnt(0)" ::: "memory");
    __builtin_amdgcn_s_setprio(1);
    #pragma unroll
    for (int i = 0; i < 4; ++i)
      #pragma unroll
      for (int c = 0; c < 4; ++c)
        acc[i][c] = mfma16(afr[i], bfr[c], acc[i][c]);
    __builtin_amdgcn_s_setprio(0);
    if (t + 2 < NT)      asm volatile("s_waitcnt vmcnt(4)" ::: "memory");
    else if (t + 1 < NT) asm volatile("s_waitcnt vmcnt(0)" ::: "memory");
    asm volatile("" ::: "memory");
    __builtin_amdgcn_s_barrier();
    asm volatile("" ::: "memory");
  }
  #undef STAGE4

  int r0 = bm + wm * 64 + ((lane >> 4) << 2);
  int c0 = bn + wn * 64 + (lane & 15);
  #pragma unroll
  for (int i = 0; i < 4; ++i){
    #pragma unroll
    for (int j = 0; j < 4; ++j){
      int cc = c0 + j * 16;
      #pragma unroll
      for (int e = 0; e < 4; ++e){
        int rr = r0 + i * 16 + e;
        size_t idx = (size_t)rr * N + cc;
        float v = acc[i][j][e];
        if (addsrc) v += addsrc[idx];
        Cf[idx] = v;
      }
    }
  }
}

// ---------------- dt = softplus(dtraw + dt_bias), fp32 path ----------------
__global__ __launch_bounds__(256) void dt_kernel(const float* __restrict__ dtraw,
                                                 const float* __restrict__ dt_bias,
                                                 float* __restrict__ dtb)
{
  int idx = blockIdx.x * 256 + threadIdx.x;
  float raw = dtraw[idx] + dt_bias[idx & 63];
  dtb[idx] = (raw > 20.f) ? raw : log1pf(expf(raw));
}

// ---------------- per (b,h,c) inclusive cumsum of dA = dt*A within chunk ----------------
__global__ __launch_bounds__(64) void acum_kernel(const float* __restrict__ dtb,
                                                  const float* __restrict__ A_log,
                                                  float* __restrict__ acum)
{
  int bid = blockIdx.x;          // (b*NH + h)*NCH + c
  int c = bid & 15;
  int hh = (bid >> 4) & 63;
  int b = bid >> 10;
  int lane = threadIdx.x;
  float Av = -expf(A_log[hh]);
  int rowbase = b * LTOT + c * CHUNK_;
  float v0 = dtb[(size_t)(rowbase + 2 * lane) * NH + hh] * Av;
  float v1 = dtb[(size_t)(rowbase + 2 * lane + 1) * NH + hh] * Av;
  float s = v0 + v1;
  #pragma unroll
  for (int d = 1; d < 64; d <<= 1){
    float t = __shfl_up(s, d, 64);
    if (lane >= d) s += t;
  }
  float excl = s - (v0 + v1);
  float* dst = acum + ((size_t)(b * NH + hh)) * LTOT + c * CHUNK_;
  dst[2 * lane]     = excl + v0;
  dst[2 * lane + 1] = excl + v0 + v1;
}

// ---------------- depthwise causal conv (width 4) + bias + SiLU; 4 l's per thread ----------------
__global__ __launch_bounds__(256) void conv_kernel(const unsigned short* __restrict__ xdt,
                                                   const float* __restrict__ cw,
                                                   const float* __restrict__ cb,
                                                   unsigned short* __restrict__ xbc)
{
  int ch = blockIdx.x * 256 + threadIdx.x;   // 17*256 = 4352 = CONVD exactly
  int l0 = blockIdx.y * 4, b = blockIdx.z;
  float x[7];
  #pragma unroll
  for (int j = 0; j < 7; j++){
    int ls = l0 - 3 + j;
    x[j] = (ls >= 0) ? b2f(xdt[((size_t)(b * LTOT + ls)) * XDTC + ch]) : 0.f;
  }
  float w0 = cw[ch * 4 + 0], w1 = cw[ch * 4 + 1], w2 = cw[ch * 4 + 2], w3 = cw[ch * 4 + 3];
  float bias = cb[ch];
  #pragma unroll
  for (int i = 0; i < 4; i++){
    float acc = bias + x[i] * w0 + x[i + 1] * w1 + x[i + 2] * w2 + x[i + 3] * w3;
    acc = acc / (1.f + expf(-acc));
    xbc[((size_t)(b * LTOT + l0 + i)) * CONVD + ch] = f2b(acc);
  }
}

// ---------------- SSD part 1: S' = (C·B^T)⊙L, Y_diag = S'·(x·dt)^T ----------------
__global__ __launch_bounds__(256) void ssd_sy_kernel(const unsigned short* __restrict__ xbc,
                                                     const float* __restrict__ dtb,
                                                     const float* __restrict__ acum,
                                                     float* __restrict__ y)
{
  int hh = blockIdx.x;
  int c = blockIdx.y >> 1;
  int half = blockIdx.y & 1;
  int b = blockIdx.z;
  __shared__ unsigned short Cs[64][136];    // C rows (l0..l0+63), later S'
  __shared__ unsigned short Bs[128][136];   // B rows (all s), later XT (rows 0..63 = p)
  __shared__ float ac[128];
  int tid = threadIdx.x, lane = tid & 63, w = tid >> 6;
  int l0 = half * 64;
  size_t rowbase = (size_t)b * LTOT + c * CHUNK_;
  if (tid < 128) ac[tid] = acum[((size_t)(b * NH + hh)) * LTOT + c * CHUNK_ + tid];
  #pragma unroll
  for (int p = 0; p < 8; p++){
    int lr = p * 8 + (tid >> 5);
    int n4 = (tid & 31) * 4;
    *(u16x4*)&Cs[lr][n4] =
      *(const u16x4*)&xbc[(rowbase + l0 + lr) * CONVD + DINNER + DSTATE + n4];
  }
  #pragma unroll
  for (int p = 0; p < 16; p++){
    int s = p * 8 + (tid >> 5);
    int n4 = (tid & 31) * 4;
    *(u16x4*)&Bs[s][n4] = *(const u16x4*)&xbc[(rowbase + s) * CONVD + DINNER + n4];
  }
  __syncthreads();
  f32x4 accS[8] = {};
  #pragma unroll
  for (int kk = 0; kk < 4; kk++){
    bf16x8 a = *(const bf16x8*)&Cs[w * 16 + (lane & 15)][kk * 32 + (lane >> 4) * 8];
    #pragma unroll
    for (int fc = 0; fc < 8; fc++){
      bf16x8 bb = *(const bf16x8*)&Bs[fc * 16 + (lane & 15)][kk * 32 + (lane >> 4) * 8];
      accS[fc] = mfma16(a, bb, accS[fc]);
    }
  }
  __syncthreads();
  // S' into Cs
  {
    int lr = w * 16 + ((lane >> 4) << 2);
    #pragma unroll
    for (int fc = 0; fc < 8; fc++){
      int s = fc * 16 + (lane & 15);
      #pragma unroll
      for (int j = 0; j < 4; j++){
        int l = l0 + lr + j;
        float v = (s <= l) ? accS[fc][j] * expf(ac[l] - ac[s]) : 0.f;
        Cs[lr + j][s] = f2b(v);
      }
    }
  }
  // XT = (x*dt)^T into Bs rows 0..63
  #pragma unroll
  for (int p = 0; p < 8; p++){
    int lr = p * 16 + (tid >> 4);
    int p4 = (tid & 15) * 4;
    float dtl = dtb[(rowbase + lr) * NH + hh];
    u16x4 v = *(const u16x4*)&xbc[(rowbase + lr) * CONVD + hh * HD + p4];
    Bs[p4 + 0][lr] = f2b(b2f(v[0]) * dtl);
    Bs[p4 + 1][lr] = f2b(b2f(v[1]) * dtl);
    Bs[p4 + 2][lr] = f2b(b2f(v[2]) * dtl);
    Bs[p4 + 3][lr] = f2b(b2f(v[3]) * dtl);
  }
  __syncthreads();
  f32x4 accY[4] = {};
  #pragma unroll
  for (int kk = 0; kk < 4; kk++){
    bf16x8 a = *(const bf16x8*)&Cs[w * 16 + (lane & 15)][kk * 32 + (lane >> 4) * 8];
    #pragma unroll
    for (int fc = 0; fc < 4; fc++){
      bf16x8 bb = *(const bf16x8*)&Bs[fc * 16 + (lane & 15)][kk * 32 + (lane >> 4) * 8];
      accY[fc] = mfma16(a, bb, accY[fc]);
    }
  }
  {
    int lr = w * 16 + ((lane >> 4) << 2);
    #pragma unroll
    for (int fc = 0; fc < 4; fc++){
      int p = fc * 16 + (lane & 15);
      #pragma unroll
      for (int j = 0; j < 4; j++){
        y[(rowbase + l0 + lr + j) * DINNER + hh * HD + p] = accY[fc][j];
      }
    }
  }
}

// ---------------- SSD part 2: states[p][n] = sum_l (x*dt*decay)[l][p] * B[l][n] ----------------
__global__ __launch_bounds__(256) void ssd_states_kernel(const unsigned short* __restrict__ xbc,
                                                         const float* __restrict__ dtb,
                                                         const float* __restrict__ acum,
                                                         unsigned short* __restrict__ states)
{
  int hh = blockIdx.x, c = blockIdx.y, b = blockIdx.z;
  __shared__ unsigned short BsT[128][136];  // [n][l]
  __shared__ unsigned short XT[64][136];    // [p][l]
  __shared__ float ac[128];
  int tid = threadIdx.x, lane = tid & 63, w = tid >> 6;
  size_t rowbase = (size_t)b * LTOT + c * CHUNK_;
  if (tid < 128) ac[tid] = acum[((size_t)(b * NH + hh)) * LTOT + c * CHUNK_ + tid];
  #pragma unroll
  for (int p = 0; p < 16; p++){
    int l = p * 8 + (tid >> 5);
    int n4 = (tid & 31) * 4;
    u16x4 v = *(const u16x4*)&xbc[(rowbase + l) * CONVD + DINNER + n4];
    BsT[n4 + 0][l] = v[0];
    BsT[n4 + 1][l] = v[1];
    BsT[n4 + 2][l] = v[2];
    BsT[n4 + 3][l] = v[3];
  }
  #pragma unroll
  for (int p = 0; p < 8; p++){
    int l = p * 16 + (tid >> 4);
    int p4 = (tid & 15) * 4;
    float dtl = dtb[(rowbase + l) * NH + hh];
    u16x4 v = *(const u16x4*)&xbc[(rowbase + l) * CONVD + hh * HD + p4];
    XT[p4 + 0][l] = f2b(b2f(v[0]) * dtl);
    XT[p4 + 1][l] = f2b(b2f(v[1]) * dtl);
    XT[p4 + 2][l] = f2b(b2f(v[2]) * dtl);
    XT[p4 + 3][l] = f2b(b2f(v[3]) * dtl);
  }
  __syncthreads();
  float aclast = ac[127];
  f32x4 accP[8] = {};
  #pragma unroll
  for (int kk = 0; kk < 4; kk++){
    int kbase = kk * 32 + (lane >> 4) * 8;
    union { u16x4 q[2]; unsigned short u[8]; bf16x8 v; } rw, ot;
    rw.q[0] = *(const u16x4*)&XT[w * 16 + (lane & 15)][kbase];
    rw.q[1] = *(const u16x4*)&XT[w * 16 + (lane & 15)][kbase + 4];
    #pragma unroll
    for (int e = 0; e < 8; e++){
      ot.u[e] = f2b(b2f(rw.u[e]) * expf(aclast - ac[kbase + e]));
    }
    #pragma unroll
    for (int fc = 0; fc < 8; fc++){
      bf16x8 bb = *(const bf16x8*)&BsT[fc * 16 + (lane & 15)][kbase];
      accP[fc] = mfma16(ot.v, bb, accP[fc]);
    }
  }
  size_t sbase = ((size_t)((b * NCH + c) * NH + hh)) * HD * DSTATE;
  int p0 = w * 16 + ((lane >> 4) << 2);
  #pragma unroll
  for (int fc = 0; fc < 8; fc++){
    int n = fc * 16 + (lane & 15);
    #pragma unroll
    for (int j = 0; j < 4; j++){
      states[sbase + (size_t)(p0 + j) * DSTATE + n] = f2b(accP[fc][j]);
    }
  }
}

// ---------------- SSD part 3: inter-chunk scan, in-place states -> prev; j split 8x ----------------
__global__ __launch_bounds__(256) void scan_kernel(unsigned short* __restrict__ states,
                                                   const float* __restrict__ acum)
{
  int bh = blockIdx.x;           // b*NH + h
  int b = bh >> 6, hh = bh & 63;
  int jg = blockIdx.y * 4;
  int t = threadIdx.x;
  float run[4] = {0.f, 0.f, 0.f, 0.f};
  for (int c = 0; c < NCH; c++){
    float alast = acum[(size_t)bh * LTOT + c * CHUNK_ + 127];
    float dec = expf(alast);
    size_t base = ((size_t)((b * NCH + c) * NH + hh)) * (HD * DSTATE);
    #pragma unroll
    for (int j = 0; j < 4; j++){
      size_t idx = base + (size_t)(jg + j) * 256 + t;
      float sc = b2f(states[idx]);
      states[idx] = f2b(run[j]);
      run[j] = run[j] * dec + sc;
    }
  }
}

// ---------------- SSD part 4: Y_off = decay[l] * C·prev^T, plus D*x, added into y ----------------
__global__ __launch_bounds__(256) void ssd3_kernel(const unsigned short* __restrict__ xbc,
                                                   const unsigned short* __restrict__ states,
                                                   const float* __restrict__ acum,
                                                   const float* __restrict__ Dp,
                                                   float* __restrict__ y)
{
  int hh = blockIdx.x, c = blockIdx.y, b = blockIdx.z;
  __shared__ unsigned short Cs[128][136];
  __shared__ unsigned short Ps[64][136];   // prev [p][n]
  __shared__ float ac[128];
  int tid = threadIdx.x, lane = tid & 63, w = tid >> 6;
  size_t rowbase = (size_t)b * LTOT + c * CHUNK_;
  if (tid < 128) ac[tid] = acum[((size_t)(b * NH + hh)) * LTOT + c * CHUNK_ + tid];
  #pragma unroll
  for (int p = 0; p < 16; p++){
    int l = p * 8 + (tid >> 5);
    int n4 = (tid & 31) * 4;
    *(u16x4*)&Cs[l][n4] =
      *(const u16x4*)&xbc[(rowbase + l) * CONVD + DINNER + DSTATE + n4];
  }
  size_t sbase = ((size_t)((b * NCH + c) * NH + hh)) * (HD * DSTATE);
  #pragma unroll
  for (int p = 0; p < 8; p++){
    int pp = p * 8 + (tid >> 5);
    int n4 = (tid & 31) * 4;
    *(u16x4*)&Ps[pp][n4] = *(const u16x4*)&states[sbase + (size_t)pp * DSTATE + n4];
  }
  __syncthreads();
  f32x4 acc[2][4] = {};
  #pragma unroll
  for (int kk = 0; kk < 4; kk++){
    bf16x8 a0 = *(const bf16x8*)&Cs[w * 32 + (lane & 15)][kk * 32 + (lane >> 4) * 8];
    bf16x8 a1 = *(const bf16x8*)&Cs[w * 32 + 16 + (lane & 15)][kk * 32 + (lane >> 4) * 8];
    #pragma unroll
    for (int fc = 0; fc < 4; fc++){
      bf16x8 bb = *(const bf16x8*)&Ps[fc * 16 + (lane & 15)][kk * 32 + (lane >> 4) * 8];
      acc[0][fc] = mfma16(a0, bb, acc[0][fc]);
      acc[1][fc] = mfma16(a1, bb, acc[1][fc]);
    }
  }
  float dpar = Dp[hh];
  #pragma unroll
  for (int fr = 0; fr < 2; fr++){
    int lr = w * 32 + fr * 16 + ((lane >> 4) << 2);
    #pragma unroll
    for (int fc = 0; fc < 4; fc++){
      int p = fc * 16 + (lane & 15);
      #pragma unroll
      for (int j = 0; j < 4; j++){
        int l = lr + j;
        size_t yi = (rowbase + l) * DINNER + hh * HD + p;
        float xsv = b2f(xbc[(rowbase + l) * CONVD + hh * HD + p]);
        y[yi] += acc[fr][fc][j] * expf(ac[l]) + dpar * xsv;
      }
    }
  }
}

extern "C" void kernel_launch(void* const* d_in, const int* in_sizes, int n_in,
                              void* d_out, int out_size, void* d_ws, size_t ws_size,
                              hipStream_t stream)
{
  (void)in_sizes; (void)n_in; (void)out_size; (void)ws_size;
  const float* hidden    = (const float*)d_in[0];
  const float* norm1_w   = (const float*)d_in[1];
  const float* in_proj_w = (const float*)d_in[2];
  const float* conv_w    = (const float*)d_in[3];
  const float* conv_b    = (const float*)d_in[4];
  const float* dt_bias   = (const float*)d_in[5];
  const float* A_log     = (const float*)d_in[6];
  const float* D_param   = (const float*)d_in[7];
  const float* mixer_w   = (const float*)d_in[8];
  const float* out_proj_w= (const float*)d_in[9];
  const float* norm2_w   = (const float*)d_in[10];
  const float* gate_w    = (const float*)d_in[11];
  const float* up_w      = (const float*)d_in[12];
  const float* down_w    = (const float*)d_in[13];

  char* ws = (char*)d_ws;
  // Workspace layout (total 175,636,480 bytes), live-range-verified aliases.
  unsigned short* zbuf    = (unsigned short*)(ws);                  // bf16 4096x4096 [k2..k10]
  unsigned short* WT_gate = (unsigned short*)(ws);                  // bf16 5632x2048 [k12.5..k13] (zbuf dead)
  unsigned short* xdt     = (unsigned short*)(ws + 33554432ull);    // bf16 4096x4416 [k2..k5]
  unsigned short* states  = (unsigned short*)(ws + 33554432ull);    // bf16 16.7M el  [k7..k9]
  unsigned short* ygn     = (unsigned short*)(ws + 33554432ull);    // bf16 4096x4096 [k10..k11]
  unsigned short* WT_up   = (unsigned short*)(ws + 33554432ull);    // bf16 5632x2048 [k13.5..k14]
  unsigned short* xbc     = (unsigned short*)(ws + 69730304ull);    // bf16 4096x4352 [k5..k9]
  unsigned short* WT_out  = (unsigned short*)(ws + 69730304ull);    // bf16 2048x4096 [k10.5..k11]
  unsigned short* h2      = (unsigned short*)(ws + 69730304ull);    // bf16 4096x2048 [k12..k14]
  unsigned short* WT_down = (unsigned short*)(ws + 69730304ull);    // bf16 2048x5632 [k14.5..k15]
  float* dtraw            = (float*)(ws + 105381888ull);            // f32 4096x64 [k2..k3]
  float* dtb              = (float*)(ws + 106430464ull);            // f32 4096x64 [k3..k9]
  float* acum             = (float*)(ws + 107479040ull);            // f32 128x2048 [k4..k9]
  float* ybuf             = (float*)(ws + 108527616ull);            // f32 4096x4096 [k6..k10]
  unsigned short* hbuf    = (unsigned short*)(ws + 108527616ull);   // bf16 4096x2048 [k1..k2]
  unsigned short* gbuf    = (unsigned short*)(ws + 108527616ull);   // bf16 4096x5632 [k13..k16]
  unsigned short* WT_in   = (unsigned short*)(ws + 125304832ull);   // bf16 8704x2048 [k0..k2]
  float* h1               = (float*)d_out;                          // f32 4096x2048 [k11..k16]
  float* outp             = (float*)d_out;

  const int dynLDS3 = 73728;   // 3 x 24KB -> 2 blocks/CU
  const int dynLDS4 = 49152;   // 3 x 16KB -> 3 blocks/CU
  hipFuncSetAttribute((const void*)gemm3_kernel,
                      hipFuncAttributeMaxDynamicSharedMemorySize, dynLDS3);
  hipFuncSetAttribute((const void*)gemm4_kernel,
                      hipFuncAttributeMaxDynamicSharedMemorySize, dynLDS4);

  // 0. convert in_proj weight -> bf16 [8704][2048] (rows >= 8512 zeroed; 8704 = 34*256)
  wconv_kernel<<<dim3(136, 32), 256, 0, stream>>>(in_proj_w, WT_in, DMODEL, INP);
  // 1. h = rmsnorm(hidden) -> bf16
  rms_kernel<<<NTOK, 256, 0, stream>>>(hidden, norm1_w, hbuf, DMODEL);
  // 2. zxbcdt = h @ in_proj: cols<4096 -> zbuf, cols>=4096 -> xdt; dt cols fp32 -> dtraw
  gemm3_kernel<<<dim3(34, 32), 512, dynLDS3, stream>>>(hbuf, WT_in, nullptr, nullptr,
                                                       zbuf, xdt, DINNER, nullptr, dtraw,
                                                       NTOK, INP, DMODEL);
  // 3. dt = softplus(dtraw + bias)
  dt_kernel<<<NTOK * NH / 256, 256, 0, stream>>>(dtraw, dt_bias, dtb);
  // 4. per-chunk cumsum of dt*A
  acum_kernel<<<BATCH * NH * NCH, 64, 0, stream>>>(dtb, A_log, acum);
  // 5. conv + silu (4 l's per thread)
  conv_kernel<<<dim3(CONVD / 256, LTOT / 4, BATCH), 256, 0, stream>>>(xdt, conv_w, conv_b, xbc);
  // 6. SSD intra-chunk: Y_diag
  ssd_sy_kernel<<<dim3(NH, NCH * 2, BATCH), 256, 0, stream>>>(xbc, dtb, acum, ybuf);
  // 7. SSD per-chunk states
  ssd_states_kernel<<<dim3(NH, NCH, BATCH), 256, 0, stream>>>(xbc, dtb, acum, states);
  // 8. inter-chunk scan (in-place -> prev), j split 8x
  scan_kernel<<<dim3(BATCH * NH, 8), 256, 0, stream>>>(states, acum);
  // 9. SSD off-diagonal + D*x
  ssd3_kernel<<<dim3(NH, NCH, BATCH), 256, 0, stream>>>(xbc, states, acum, D_param, ybuf);
  // 10. gated rmsnorm: ygn = rmsnorm(y * silu(z))
  rms_gated_kernel<<<NTOK, 256, 0, stream>>>(ybuf, zbuf, mixer_w, ygn);
  // 10.5 convert out_proj weight (xbc region dead)
  wconv_kernel<<<dim3(32, 64), 256, 0, stream>>>(out_proj_w, WT_out, DINNER, DMODEL);
  // 11. h1 = hidden + ygn @ out_proj  (into d_out); 512 blocks, 3/CU
  gemm4_kernel<<<dim3(16, 32), 256, dynLDS4, stream>>>(ygn, WT_out, hidden, h1,
                                                       NTOK, DMODEL, DINNER);
  // 12. h2 = rmsnorm(h1) -> bf16
  rms_kernel<<<NTOK, 256, 0, stream>>>(h1, norm2_w, h2, DMODEL);
  // 12.5 convert gate weight (zbuf dead)
  wconv_kernel<<<dim3(88, 32), 256, 0, stream>>>(gate_w, WT_gate, DMODEL, INTER_);
  // 13. g = h2 @ gate_w -> gbuf (bf16)
  gemm3_kernel<<<dim3(22, 32), 512, dynLDS3, stream>>>(h2, WT_gate, nullptr, nullptr,
                                                       gbuf, nullptr, INTER_, nullptr, nullptr,
                                                       NTOK, INTER_, DMODEL);
  // 13.5 convert up weight (xdt/ygn dead)
  wconv_kernel<<<dim3(88, 32), 256, 0, stream>>>(up_w, WT_up, DMODEL, INTER_);
  // 14. u = h2 @ up_w, fused: gbuf = silu(gbuf) * u
  gemm3_kernel<<<dim3(22, 32), 512, dynLDS3, stream>>>(h2, WT_up, nullptr, nullptr,
                                                       gbuf, nullptr, INTER_, gbuf, nullptr,
                                                       NTOK, INTER_, DMODEL);
  // 14.5 convert down weight (h2 dead)
  wconv_kernel<<<dim3(32, 88), 256, 0, stream>>>(down_w, WT_down, INTER_, DMODEL);
  // 15. out = h1 + (g*u) @ down_w  (in place on d_out); 512 blocks, 3/CU
  gemm4_kernel<<<dim3(16, 32), 256, dynLDS4, stream>>>(gbuf, WT_down, h1, outp,
                                                       NTOK, DMODEL, INTER_);
}

// Round 9
// 1011.949 us; speedup vs baseline: 1.3496x; 1.0242x over previous
//
#include <hip/hip_runtime.h>

#define LTOT 2048
#define BATCH 2
#define NTOK 4096
#define DMODEL 2048
#define DSTATE 128
#define NH 64
#define HD 64
#define DINNER 4096
#define CONVD 4352
#define XDTC 4416
#define INP 8512
#define INTER_ 5632
#define CHUNK_ 128
#define NCH 16
#define EPSF 1e-6f

typedef __bf16 bf16x8 __attribute__((ext_vector_type(8)));
typedef float f32x4 __attribute__((ext_vector_type(4)));
typedef unsigned short u16x4 __attribute__((ext_vector_type(4)));
typedef unsigned short u16x8 __attribute__((ext_vector_type(8)));

__device__ __forceinline__ unsigned short f2b(float f){
  unsigned int u = __builtin_bit_cast(unsigned int, f);
  u += 0x7fffu + ((u >> 16) & 1u);
  return (unsigned short)(u >> 16);
}
__device__ __forceinline__ float b2f(unsigned short h){
  return __builtin_bit_cast(float, ((unsigned int)h) << 16);
}
__device__ __forceinline__ f32x4 mfma16(bf16x8 a, bf16x8 b, f32x4 c){
  return __builtin_amdgcn_mfma_f32_16x16x32_bf16(a, b, c, 0, 0, 0);
}
// async global->LDS, 16B per lane, wave-uniform LDS base + lane*16
typedef const __attribute__((address_space(1))) void* gas_t;
typedef __attribute__((address_space(3))) void* las_t;
__device__ __forceinline__ void gload16(const void* g, void* l){
  __builtin_amdgcn_global_load_lds((gas_t)g, (las_t)l, 16, 0, 0);
}

// ---------------- weight convert: fp32 W[K][N] -> bf16 WT[Npad][K], zero rows n>=N ----------------
__global__ __launch_bounds__(256) void wconv_kernel(const float* __restrict__ W,
                                                    unsigned short* __restrict__ WT,
                                                    int K, int N)
{
  __shared__ unsigned short t[64][72];
  int n0 = blockIdx.x * 64, k0 = blockIdx.y * 64;
  int tid = threadIdx.x;
  int kl = tid >> 4, nl4 = (tid & 15) * 4;
  #pragma unroll
  for (int it = 0; it < 4; it++){
    int kk = kl + it * 16;
    float4 v = make_float4(0.f, 0.f, 0.f, 0.f);
    if (n0 < N) v = *(const float4*)&W[(size_t)(k0 + kk) * N + n0 + nl4];
    t[nl4 + 0][kk] = f2b(v.x);
    t[nl4 + 1][kk] = f2b(v.y);
    t[nl4 + 2][kk] = f2b(v.z);
    t[nl4 + 3][kk] = f2b(v.w);
  }
  __syncthreads();
  int nr = tid >> 3, k8 = (tid & 7) * 8;
  #pragma unroll
  for (int it = 0; it < 2; it++){
    int nn = nr + it * 32;
    *(u16x8*)&WT[(size_t)(n0 + nn) * K + k0 + k8] = *(const u16x8*)&t[nn][k8];
  }
}

// ---------------- RMSNorm: fp32 in -> bf16 out ----------------
__global__ __launch_bounds__(256) void rms_kernel(const float* __restrict__ x,
                                                  const float* __restrict__ w,
                                                  unsigned short* __restrict__ out, int width)
{
  int row = blockIdx.x, tid = threadIdx.x;
  const float* xr = x + (size_t)row * width;
  unsigned short* orow = out + (size_t)row * width;
  int nv = width >> 2;
  float ss = 0.f;
  for (int i = tid; i < nv; i += 256){
    float4 v = ((const float4*)xr)[i];
    ss += v.x*v.x + v.y*v.y + v.z*v.z + v.w*v.w;
  }
  #pragma unroll
  for (int off = 32; off > 0; off >>= 1) ss += __shfl_down(ss, off, 64);
  __shared__ float red[4];
  if ((tid & 63) == 0) red[tid >> 6] = ss;
  __syncthreads();
  float tot = red[0] + red[1] + red[2] + red[3];
  float scale = rsqrtf(tot / (float)width + EPSF);
  for (int i = tid; i < nv; i += 256){
    float4 v = ((const float4*)xr)[i];
    float4 wv = ((const float4*)w)[i];
    u16x4 o = { f2b(v.x * scale * wv.x), f2b(v.y * scale * wv.y),
                f2b(v.z * scale * wv.z), f2b(v.w * scale * wv.w) };
    ((u16x4*)orow)[i] = o;
  }
}

// ---------------- Gated RMSNorm: y fp32, z bf16 -> out bf16 ----------------
__global__ __launch_bounds__(256) void rms_gated_kernel(const float* __restrict__ y,
                                                        const unsigned short* __restrict__ z,
                                                        const float* __restrict__ w,
                                                        unsigned short* __restrict__ out)
{
  int row = blockIdx.x, tid = threadIdx.x;
  const float* yr = y + (size_t)row * DINNER;
  const unsigned short* zr = z + (size_t)row * DINNER;
  unsigned short* orow = out + (size_t)row * DINNER;
  float g[16];
  float ss = 0.f;
  #pragma unroll
  for (int ii = 0; ii < 4; ii++){
    int i = tid + ii * 256;
    float4 yv = ((const float4*)yr)[i];
    u16x4 zv = ((const u16x4*)zr)[i];
    #pragma unroll
    for (int e = 0; e < 4; e++){
      float zf = b2f(zv[e]);
      float yf = (&yv.x)[e];
      float gg = yf * (zf / (1.f + expf(-zf)));
      g[ii * 4 + e] = gg;
      ss += gg * gg;
    }
  }
  #pragma unroll
  for (int off = 32; off > 0; off >>= 1) ss += __shfl_down(ss, off, 64);
  __shared__ float red[4];
  if ((tid & 63) == 0) red[tid >> 6] = ss;
  __syncthreads();
  float tot = red[0] + red[1] + red[2] + red[3];
  float scale = rsqrtf(tot / (float)DINNER + EPSF);
  #pragma unroll
  for (int ii = 0; ii < 4; ii++){
    int i = tid + ii * 256;
    float4 wv = ((const float4*)w)[i];
    u16x4 o;
    #pragma unroll
    for (int e = 0; e < 4; e++) o[e] = f2b(g[ii * 4 + e] * scale * (&wv.x)[e]);
    ((u16x4*)orow)[i] = o;
  }
}

// ---------------- SwiGLU combine: g = silu(g) * u, bf16 ----------------
__global__ __launch_bounds__(256) void act_kernel(unsigned short* __restrict__ g,
                                                  const unsigned short* __restrict__ u, int n8)
{
  int stride = gridDim.x * 256;
  for (int i = blockIdx.x * 256 + threadIdx.x; i < n8; i += stride){
    u16x8 gv = ((const u16x8*)g)[i];
    u16x8 uv = ((const u16x8*)u)[i];
    u16x8 o;
    #pragma unroll
    for (int e = 0; e < 8; e++){
      float gf = b2f(gv[e]);
      o[e] = f2b(gf / (1.f + expf(-gf)) * b2f(uv[e]));
    }
    ((u16x8*)g)[i] = o;
  }
}

// ---------------- GEMM3: 128(M)x256(N), BK=32, 8 waves, 3-buf counted-vmcnt, ONE barrier/tile ----
// No explicit lgkmcnt drain: compiler inserts fine-grained per-operand waits (m97 asm evidence),
// letting first MFMAs start while later ds_reads are still in flight.
__global__ __launch_bounds__(512, 2) void gemm3_kernel(const unsigned short* __restrict__ A,
                                                       const unsigned short* __restrict__ BT,
                                                       const float* __restrict__ addsrc,
                                                       float* __restrict__ Cf,
                                                       unsigned short* __restrict__ Cb,
                                                       unsigned short* __restrict__ Cb2, int splitN,
                                                       const unsigned short* __restrict__ gate,
                                                       float* __restrict__ dtraw,
                                                       int M, int N, int K)
{
  extern __shared__ unsigned short lds[];    // 36864 u16 = 72KB; buf i at i*12288 (A 4096, B 8192 u16)
  int tid = threadIdx.x, lane = tid & 63, w = tid >> 6;
  int wm = w >> 2, wn = w & 3;               // wave grid 2(M) x 4(N); wave block 64x64
  int bid = blockIdx.x + blockIdx.y * gridDim.x;
  int nwg = gridDim.x * gridDim.y;
  int q8 = nwg >> 3, r8 = nwg & 7;
  int xcd = bid & 7, boff = bid >> 3;
  int wgid = (xcd < r8 ? xcd * (q8 + 1) : r8 * (q8 + 1) + (xcd - r8) * q8) + boff;
  int bn = (wgid % gridDim.x) * 256;
  int bm = (wgid / gridDim.x) * 128;

  int soct8 = ((lane & 3) ^ ((lane >> 2) & 3)) << 3;   // staging source k-offset (pre-swizzled)
  int prow_l = (lane >> 2);
  int ko = (((lane >> 4) ^ (lane & 3)) << 3);          // read-side swizzled k-offset
  int rsel = (lane & 15) * 32 + ko;

  f32x4 acc[4][4] = {};
  int NT = K >> 5;

  #define STAGE(kt, bsel)                                                              \
    {                                                                                  \
      unsigned short* bb_ = &lds[(bsel) * 12288];                                      \
      size_t k0_ = (size_t)(kt) << 5;                                                  \
      gload16(&A [(size_t)(bm +       w * 16 + prow_l) * K + k0_ + soct8], &bb_[w * 512]);            \
      gload16(&BT[(size_t)(bn +       w * 16 + prow_l) * K + k0_ + soct8], &bb_[4096 + w * 512]);     \
      gload16(&BT[(size_t)(bn + 128 + w * 16 + prow_l) * K + k0_ + soct8], &bb_[8192 + w * 512]);     \
    }

  STAGE(0, 0)
  STAGE(1, 1)
  asm volatile("s_waitcnt vmcnt(3)" ::: "memory");
  __builtin_amdgcn_s_barrier();
  asm volatile("" ::: "memory");

  for (int t = 0; t < NT; ++t){
    const unsigned short* bufc = &lds[(t % 3) * 12288];
    bf16x8 afr[4], bfr[4];
    #pragma unroll
    for (int i = 0; i < 4; ++i)
      afr[i] = *(const bf16x8*)&bufc[(wm * 64 + i * 16) * 32 + rsel];
    #pragma unroll
    for (int c = 0; c < 4; ++c)
      bfr[c] = *(const bf16x8*)&bufc[4096 + (wn * 64 + c * 16) * 32 + rsel];
    if (t + 2 < NT) STAGE(t + 2, (t + 2) % 3)
    __builtin_amdgcn_s_setprio(1);
    #pragma unroll
    for (int i = 0; i < 4; ++i)
      #pragma unroll
      for (int c = 0; c < 4; ++c)
        acc[i][c] = mfma16(afr[i], bfr[c], acc[i][c]);
    __builtin_amdgcn_s_setprio(0);
    if (t + 2 < NT)      asm volatile("s_waitcnt vmcnt(3)" ::: "memory");  // t+1 landed
    else if (t + 1 < NT) asm volatile("s_waitcnt vmcnt(0)" ::: "memory");  // final drain
    asm volatile("" ::: "memory");
    __builtin_amdgcn_s_barrier();
    asm volatile("" ::: "memory");
  }
  #undef STAGE

  int r0 = bm + wm * 64 + ((lane >> 4) << 2);
  int c0 = bn + wn * 64 + (lane & 15);
  #pragma unroll
  for (int i = 0; i < 4; ++i){
    #pragma unroll
    for (int j = 0; j < 4; ++j){
      int cc = c0 + j * 16;
      if (cc < N){
        #pragma unroll
        for (int e = 0; e < 4; ++e){
          int rr = r0 + i * 16 + e;
          float v = acc[i][j][e];
          if (Cf){
            size_t idx = (size_t)rr * N + cc;
            if (addsrc) v += addsrc[idx];
            Cf[idx] = v;
          } else if (cc < splitN){
            size_t idx = (size_t)rr * splitN + cc;
            float vv = v;
            if (gate){ float gg = b2f(gate[idx]); vv = gg / (1.f + expf(-gg)) * v; }
            Cb[idx] = f2b(vv);
          } else {
            Cb2[(size_t)rr * (N - splitN) + (cc - splitN)] = f2b(v);
            if (dtraw && cc >= N - NH) dtraw[(size_t)rr * NH + (cc - (N - NH))] = v;
          }
        }
      }
    }
  }
}

// ---------------- GEMM4: 128(M)x128(N), BK=32, 4 waves (2x2), 3x16KB bufs -> 3 blocks/CU -------
__global__ __launch_bounds__(256, 3) void gemm4_kernel(const unsigned short* __restrict__ A,
                                                       const unsigned short* __restrict__ BT,
                                                       const float* __restrict__ addsrc,
                                                       float* __restrict__ Cf,
                                                       int M, int N, int K)
{
  extern __shared__ unsigned short lds[];    // 24576 u16 = 48KB; buf i at i*8192 (A 4096, B 4096)
  int tid = threadIdx.x, lane = tid & 63, w = tid >> 6;
  int wm = w >> 1, wn = w & 1;               // wave grid 2(M) x 2(N); wave block 64x64
  int bid = blockIdx.x + blockIdx.y * gridDim.x;
  int nwg = gridDim.x * gridDim.y;
  int q8 = nwg >> 3, r8 = nwg & 7;
  int xcd = bid & 7, boff = bid >> 3;
  int wgid = (xcd < r8 ? xcd * (q8 + 1) : r8 * (q8 + 1) + (xcd - r8) * q8) + boff;
  int bn = (wgid % gridDim.x) * 128;
  int bm = (wgid / gridDim.x) * 128;

  int soct8 = ((lane & 3) ^ ((lane >> 2) & 3)) << 3;
  int prow_l = (lane >> 2);
  int ko = (((lane >> 4) ^ (lane & 3)) << 3);
  int rsel = (lane & 15) * 32 + ko;

  f32x4 acc[4][4] = {};
  int NT = K >> 5;

  #define STAGE4(kt, bsel)                                                             \
    {                                                                                  \
      unsigned short* bb_ = &lds[(bsel) * 8192];                                       \
      size_t k0_ = (size_t)(kt) << 5;                                                  \
      gload16(&A [(size_t)(bm +      w * 16 + prow_l) * K + k0_ + soct8], &bb_[w * 512]);          \
      gload16(&A [(size_t)(bm + 64 + w * 16 + prow_l) * K + k0_ + soct8], &bb_[2048 + w * 512]);   \
      gload16(&BT[(size_t)(bn +      w * 16 + prow_l) * K + k0_ + soct8], &bb_[4096 + w * 512]);   \
      gload16(&BT[(size_t)(bn + 64 + w * 16 + prow_l) * K + k0_ + soct8], &bb_[6144 + w * 512]);   \
    }

  STAGE4(0, 0)
  STAGE4(1, 1)
  asm volatile("s_waitcnt vmcnt(4)" ::: "memory");
  __builtin_amdgcn_s_barrier();
  asm volatile("" ::: "memory");

  for (int t = 0; t < NT; ++t){
    const unsigned short* bufc = &lds[(t % 3) * 8192];
    bf16x8 afr[4], bfr[4];
    #pragma unroll
    for (int i = 0; i < 4; ++i)
      afr[i] = *(const bf16x8*)&bufc[(wm * 64 + i * 16) * 32 + rsel];
    #pragma unroll
    for (int c = 0; c < 4; ++c)
      bfr[c] = *(const bf16x8*)&bufc[4096 + (wn * 64 + c * 16) * 32 + rsel];
    if (t + 2 < NT) STAGE4(t + 2, (t + 2) % 3)
    __builtin_amdgcn_s_setprio(1);
    #pragma unroll
    for (int i = 0; i < 4; ++i)
      #pragma unroll
      for (int c = 0; c < 4; ++c)
        acc[i][c] = mfma16(afr[i], bfr[c], acc[i][c]);
    __builtin_amdgcn_s_setprio(0);
    if (t + 2 < NT)      asm volatile("s_waitcnt vmcnt(4)" ::: "memory");
    else if (t + 1 < NT) asm volatile("s_waitcnt vmcnt(0)" ::: "memory");
    asm volatile("" ::: "memory");
    __builtin_amdgcn_s_barrier();
    asm volatile("" ::: "memory");
  }
  #undef STAGE4

  int r0 = bm + wm * 64 + ((lane >> 4) << 2);
  int c0 = bn + wn * 64 + (lane & 15);
  #pragma unroll
  for (int i = 0; i < 4; ++i){
    #pragma unroll
    for (int j = 0; j < 4; ++j){
      int cc = c0 + j * 16;
      #pragma unroll
      for (int e = 0; e < 4; ++e){
        int rr = r0 + i * 16 + e;
        size_t idx = (size_t)rr * N + cc;
        float v = acc[i][j][e];
        if (addsrc) v += addsrc[idx];
        Cf[idx] = v;
      }
    }
  }
}

// ---------------- dt = softplus(dtraw + dt_bias), fp32 path ----------------
__global__ __launch_bounds__(256) void dt_kernel(const float* __restrict__ dtraw,
                                                 const float* __restrict__ dt_bias,
                                                 float* __restrict__ dtb)
{
  int idx = blockIdx.x * 256 + threadIdx.x;
  float raw = dtraw[idx] + dt_bias[idx & 63];
  dtb[idx] = (raw > 20.f) ? raw : log1pf(expf(raw));
}

// ---------------- per (b,h,c) inclusive cumsum of dA = dt*A within chunk ----------------
__global__ __launch_bounds__(64) void acum_kernel(const float* __restrict__ dtb,
                                                  const float* __restrict__ A_log,
                                                  float* __restrict__ acum)
{
  int bid = blockIdx.x;          // (b*NH + h)*NCH + c
  int c = bid & 15;
  int hh = (bid >> 4) & 63;
  int b = bid >> 10;
  int lane = threadIdx.x;
  float Av = -expf(A_log[hh]);
  int rowbase = b * LTOT + c * CHUNK_;
  float v0 = dtb[(size_t)(rowbase + 2 * lane) * NH + hh] * Av;
  float v1 = dtb[(size_t)(rowbase + 2 * lane + 1) * NH + hh] * Av;
  float s = v0 + v1;
  #pragma unroll
  for (int d = 1; d < 64; d <<= 1){
    float t = __shfl_up(s, d, 64);
    if (lane >= d) s += t;
  }
  float excl = s - (v0 + v1);
  float* dst = acum + ((size_t)(b * NH + hh)) * LTOT + c * CHUNK_;
  dst[2 * lane]     = excl + v0;
  dst[2 * lane + 1] = excl + v0 + v1;
}

// ---------------- depthwise causal conv (width 4) + bias + SiLU; 4 l's per thread ----------------
__global__ __launch_bounds__(256) void conv_kernel(const unsigned short* __restrict__ xdt,
                                                   const float* __restrict__ cw,
                                                   const float* __restrict__ cb,
                                                   unsigned short* __restrict__ xbc)
{
  int ch = blockIdx.x * 256 + threadIdx.x;   // 17*256 = 4352 = CONVD exactly
  int l0 = blockIdx.y * 4, b = blockIdx.z;
  float x[7];
  #pragma unroll
  for (int j = 0; j < 7; j++){
    int ls = l0 - 3 + j;
    x[j] = (ls >= 0) ? b2f(xdt[((size_t)(b * LTOT + ls)) * XDTC + ch]) : 0.f;
  }
  float w0 = cw[ch * 4 + 0], w1 = cw[ch * 4 + 1], w2 = cw[ch * 4 + 2], w3 = cw[ch * 4 + 3];
  float bias = cb[ch];
  #pragma unroll
  for (int i = 0; i < 4; i++){
    float acc = bias + x[i] * w0 + x[i + 1] * w1 + x[i + 2] * w2 + x[i + 3] * w3;
    acc = acc / (1.f + expf(-acc));
    xbc[((size_t)(b * LTOT + l0 + i)) * CONVD + ch] = f2b(acc);
  }
}

// ---------------- SSD part 1: S' = (C·B^T)⊙L, Y_diag = S'·(x·dt)^T ----------------
__global__ __launch_bounds__(256) void ssd_sy_kernel(const unsigned short* __restrict__ xbc,
                                                     const float* __restrict__ dtb,
                                                     const float* __restrict__ acum,
                                                     float* __restrict__ y)
{
  int hh = blockIdx.x;
  int c = blockIdx.y >> 1;
  int half = blockIdx.y & 1;
  int b = blockIdx.z;
  __shared__ unsigned short Cs[64][136];    // C rows (l0..l0+63), later S'
  __shared__ unsigned short Bs[128][136];   // B rows (all s), later XT (rows 0..63 = p)
  __shared__ float ac[128];
  int tid = threadIdx.x, lane = tid & 63, w = tid >> 6;
  int l0 = half * 64;
  size_t rowbase = (size_t)b * LTOT + c * CHUNK_;
  if (tid < 128) ac[tid] = acum[((size_t)(b * NH + hh)) * LTOT + c * CHUNK_ + tid];
  #pragma unroll
  for (int p = 0; p < 8; p++){
    int lr = p * 8 + (tid >> 5);
    int n4 = (tid & 31) * 4;
    *(u16x4*)&Cs[lr][n4] =
      *(const u16x4*)&xbc[(rowbase + l0 + lr) * CONVD + DINNER + DSTATE + n4];
  }
  #pragma unroll
  for (int p = 0; p < 16; p++){
    int s = p * 8 + (tid >> 5);
    int n4 = (tid & 31) * 4;
    *(u16x4*)&Bs[s][n4] = *(const u16x4*)&xbc[(rowbase + s) * CONVD + DINNER + n4];
  }
  __syncthreads();
  f32x4 accS[8] = {};
  #pragma unroll
  for (int kk = 0; kk < 4; kk++){
    bf16x8 a = *(const bf16x8*)&Cs[w * 16 + (lane & 15)][kk * 32 + (lane >> 4) * 8];
    #pragma unroll
    for (int fc = 0; fc < 8; fc++){
      bf16x8 bb = *(const bf16x8*)&Bs[fc * 16 + (lane & 15)][kk * 32 + (lane >> 4) * 8];
      accS[fc] = mfma16(a, bb, accS[fc]);
    }
  }
  __syncthreads();
  // S' into Cs
  {
    int lr = w * 16 + ((lane >> 4) << 2);
    #pragma unroll
    for (int fc = 0; fc < 8; fc++){
      int s = fc * 16 + (lane & 15);
      #pragma unroll
      for (int j = 0; j < 4; j++){
        int l = l0 + lr + j;
        float v = (s <= l) ? accS[fc][j] * expf(ac[l] - ac[s]) : 0.f;
        Cs[lr + j][s] = f2b(v);
      }
    }
  }
  // XT = (x*dt)^T into Bs rows 0..63
  #pragma unroll
  for (int p = 0; p < 8; p++){
    int lr = p * 16 + (tid >> 4);
    int p4 = (tid & 15) * 4;
    float dtl = dtb[(rowbase + lr) * NH + hh];
    u16x4 v = *(const u16x4*)&xbc[(rowbase + lr) * CONVD + hh * HD + p4];
    Bs[p4 + 0][lr] = f2b(b2f(v[0]) * dtl);
    Bs[p4 + 1][lr] = f2b(b2f(v[1]) * dtl);
    Bs[p4 + 2][lr] = f2b(b2f(v[2]) * dtl);
    Bs[p4 + 3][lr] = f2b(b2f(v[3]) * dtl);
  }
  __syncthreads();
  f32x4 accY[4] = {};
  #pragma unroll
  for (int kk = 0; kk < 4; kk++){
    bf16x8 a = *(const bf16x8*)&Cs[w * 16 + (lane & 15)][kk * 32 + (lane >> 4) * 8];
    #pragma unroll
    for (int fc = 0; fc < 4; fc++){
      bf16x8 bb = *(const bf16x8*)&Bs[fc * 16 + (lane & 15)][kk * 32 + (lane >> 4) * 8];
      accY[fc] = mfma16(a, bb, accY[fc]);
    }
  }
  {
    int lr = w * 16 + ((lane >> 4) << 2);
    #pragma unroll
    for (int fc = 0; fc < 4; fc++){
      int p = fc * 16 + (lane & 15);
      #pragma unroll
      for (int j = 0; j < 4; j++){
        y[(rowbase + l0 + lr + j) * DINNER + hh * HD + p] = accY[fc][j];
      }
    }
  }
}

// ---------------- SSD part 2: states[p][n] = sum_l (x*dt*decay)[l][p] * B[l][n] ----------------
__global__ __launch_bounds__(256) void ssd_states_kernel(const unsigned short* __restrict__ xbc,
                                                         const float* __restrict__ dtb,
                                                         const float* __restrict__ acum,
                                                         unsigned short* __restrict__ states)
{
  int hh = blockIdx.x, c = blockIdx.y, b = blockIdx.z;
  __shared__ unsigned short BsT[128][136];  // [n][l]
  __shared__ unsigned short XT[64][136];    // [p][l]
  __shared__ float ac[128];
  int tid = threadIdx.x, lane = tid & 63, w = tid >> 6;
  size_t rowbase = (size_t)b * LTOT + c * CHUNK_;
  if (tid < 128) ac[tid] = acum[((size_t)(b * NH + hh)) * LTOT + c * CHUNK_ + tid];
  #pragma unroll
  for (int p = 0; p < 16; p++){
    int l = p * 8 + (tid >> 5);
    int n4 = (tid & 31) * 4;
    u16x4 v = *(const u16x4*)&xbc[(rowbase + l) * CONVD + DINNER + n4];
    BsT[n4 + 0][l] = v[0];
    BsT[n4 + 1][l] = v[1];
    BsT[n4 + 2][l] = v[2];
    BsT[n4 + 3][l] = v[3];
  }
  #pragma unroll
  for (int p = 0; p < 8; p++){
    int l = p * 16 + (tid >> 4);
    int p4 = (tid & 15) * 4;
    float dtl = dtb[(rowbase + l) * NH + hh];
    u16x4 v = *(const u16x4*)&xbc[(rowbase + l) * CONVD + hh * HD + p4];
    XT[p4 + 0][l] = f2b(b2f(v[0]) * dtl);
    XT[p4 + 1][l] = f2b(b2f(v[1]) * dtl);
    XT[p4 + 2][l] = f2b(b2f(v[2]) * dtl);
    XT[p4 + 3][l] = f2b(b2f(v[3]) * dtl);
  }
  __syncthreads();
  float aclast = ac[127];
  f32x4 accP[8] = {};
  #pragma unroll
  for (int kk = 0; kk < 4; kk++){
    int kbase = kk * 32 + (lane >> 4) * 8;
    union { u16x4 q[2]; unsigned short u[8]; bf16x8 v; } rw, ot;
    rw.q[0] = *(const u16x4*)&XT[w * 16 + (lane & 15)][kbase];
    rw.q[1] = *(const u16x4*)&XT[w * 16 + (lane & 15)][kbase + 4];
    #pragma unroll
    for (int e = 0; e < 8; e++){
      ot.u[e] = f2b(b2f(rw.u[e]) * expf(aclast - ac[kbase + e]));
    }
    #pragma unroll
    for (int fc = 0; fc < 8; fc++){
      bf16x8 bb = *(const bf16x8*)&BsT[fc * 16 + (lane & 15)][kbase];
      accP[fc] = mfma16(ot.v, bb, accP[fc]);
    }
  }
  size_t sbase = ((size_t)((b * NCH + c) * NH + hh)) * HD * DSTATE;
  int p0 = w * 16 + ((lane >> 4) << 2);
  #pragma unroll
  for (int fc = 0; fc < 8; fc++){
    int n = fc * 16 + (lane & 15);
    #pragma unroll
    for (int j = 0; j < 4; j++){
      states[sbase + (size_t)(p0 + j) * DSTATE + n] = f2b(accP[fc][j]);
    }
  }
}

// ---------------- SSD part 3: inter-chunk scan, in-place states -> prev; j split 8x ----------------
__global__ __launch_bounds__(256) void scan_kernel(unsigned short* __restrict__ states,
                                                   const float* __restrict__ acum)
{
  int bh = blockIdx.x;           // b*NH + h
  int b = bh >> 6, hh = bh & 63;
  int jg = blockIdx.y * 4;
  int t = threadIdx.x;
  float run[4] = {0.f, 0.f, 0.f, 0.f};
  for (int c = 0; c < NCH; c++){
    float alast = acum[(size_t)bh * LTOT + c * CHUNK_ + 127];
    float dec = expf(alast);
    size_t base = ((size_t)((b * NCH + c) * NH + hh)) * (HD * DSTATE);
    #pragma unroll
    for (int j = 0; j < 4; j++){
      size_t idx = base + (size_t)(jg + j) * 256 + t;
      float sc = b2f(states[idx]);
      states[idx] = f2b(run[j]);
      run[j] = run[j] * dec + sc;
    }
  }
}

// ---------------- SSD part 4: Y_off = decay[l] * C·prev^T, plus D*x, added into y ----------------
__global__ __launch_bounds__(256) void ssd3_kernel(const unsigned short* __restrict__ xbc,
                                                   const unsigned short* __restrict__ states,
                                                   const float* __restrict__ acum,
                                                   const float* __restrict__ Dp,
                                                   float* __restrict__ y)
{
  int hh = blockIdx.x, c = blockIdx.y, b = blockIdx.z;
  __shared__ unsigned short Cs[128][136];
  __shared__ unsigned short Ps[64][136];   // prev [p][n]
  __shared__ float ac[128];
  int tid = threadIdx.x, lane = tid & 63, w = tid >> 6;
  size_t rowbase = (size_t)b * LTOT + c * CHUNK_;
  if (tid < 128) ac[tid] = acum[((size_t)(b * NH + hh)) * LTOT + c * CHUNK_ + tid];
  #pragma unroll
  for (int p = 0; p < 16; p++){
    int l = p * 8 + (tid >> 5);
    int n4 = (tid & 31) * 4;
    *(u16x4*)&Cs[l][n4] =
      *(const u16x4*)&xbc[(rowbase + l) * CONVD + DINNER + DSTATE + n4];
  }
  size_t sbase = ((size_t)((b * NCH + c) * NH + hh)) * (HD * DSTATE);
  #pragma unroll
  for (int p = 0; p < 8; p++){
    int pp = p * 8 + (tid >> 5);
    int n4 = (tid & 31) * 4;
    *(u16x4*)&Ps[pp][n4] = *(const u16x4*)&states[sbase + (size_t)pp * DSTATE + n4];
  }
  __syncthreads();
  f32x4 acc[2][4] = {};
  #pragma unroll
  for (int kk = 0; kk < 4; kk++){
    bf16x8 a0 = *(const bf16x8*)&Cs[w * 32 + (lane & 15)][kk * 32 + (lane >> 4) * 8];
    bf16x8 a1 = *(const bf16x8*)&Cs[w * 32 + 16 + (lane & 15)][kk * 32 + (lane >> 4) * 8];
    #pragma unroll
    for (int fc = 0; fc < 4; fc++){
      bf16x8 bb = *(const bf16x8*)&Ps[fc * 16 + (lane & 15)][kk * 32 + (lane >> 4) * 8];
      acc[0][fc] = mfma16(a0, bb, acc[0][fc]);
      acc[1][fc] = mfma16(a1, bb, acc[1][fc]);
    }
  }
  float dpar = Dp[hh];
  #pragma unroll
  for (int fr = 0; fr < 2; fr++){
    int lr = w * 32 + fr * 16 + ((lane >> 4) << 2);
    #pragma unroll
    for (int fc = 0; fc < 4; fc++){
      int p = fc * 16 + (lane & 15);
      #pragma unroll
      for (int j = 0; j < 4; j++){
        int l = lr + j;
        size_t yi = (rowbase + l) * DINNER + hh * HD + p;
        float xsv = b2f(xbc[(rowbase + l) * CONVD + hh * HD + p]);
        y[yi] += acc[fr][fc][j] * expf(ac[l]) + dpar * xsv;
      }
    }
  }
}

extern "C" void kernel_launch(void* const* d_in, const int* in_sizes, int n_in,
                              void* d_out, int out_size, void* d_ws, size_t ws_size,
                              hipStream_t stream)
{
  (void)in_sizes; (void)n_in; (void)out_size; (void)ws_size;
  const float* hidden    = (const float*)d_in[0];
  const float* norm1_w   = (const float*)d_in[1];
  const float* in_proj_w = (const float*)d_in[2];
  const float* conv_w    = (const float*)d_in[3];
  const float* conv_b    = (const float*)d_in[4];
  const float* dt_bias   = (const float*)d_in[5];
  const float* A_log     = (const float*)d_in[6];
  const float* D_param   = (const float*)d_in[7];
  const float* mixer_w   = (const float*)d_in[8];
  const float* out_proj_w= (const float*)d_in[9];
  const float* norm2_w   = (const float*)d_in[10];
  const float* gate_w    = (const float*)d_in[11];
  const float* up_w      = (const float*)d_in[12];
  const float* down_w    = (const float*)d_in[13];

  char* ws = (char*)d_ws;
  // Workspace layout (175,636,480 bytes), live ranges re-verified for this round:
  unsigned short* zbuf    = (unsigned short*)(ws);                  // bf16 4096x4096 [k2..k10]
  unsigned short* WT_cat  = (unsigned short*)(ws);                  // bf16 11264x2048 [k12.5..k13] (zbuf/xdt dead)
  unsigned short* WT_down = (unsigned short*)(ws);                  // bf16 2048x5632 [k14..k15] (WT_cat dead)
  unsigned short* xdt     = (unsigned short*)(ws + 33554432ull);    // bf16 4096x4416 [k2..k5]
  unsigned short* states  = (unsigned short*)(ws + 33554432ull);    // bf16 16.7M el  [k7..k9]
  unsigned short* ygn     = (unsigned short*)(ws + 33554432ull);    // bf16 4096x4096 [k10..k11]
  unsigned short* ubuf    = (unsigned short*)(ws + 46137344ull);    // bf16 4096x5632 [k13..k13.5] (xdt/xbc tails dead)
  unsigned short* xbc     = (unsigned short*)(ws + 69730304ull);    // bf16 4096x4352 [k5..k9]
  unsigned short* WT_out  = (unsigned short*)(ws + 69730304ull);    // bf16 2048x4096 [k10.5..k11]
  float* dtraw            = (float*)(ws + 105381888ull);            // f32 4096x64 [k2..k3]
  float* dtb              = (float*)(ws + 106430464ull);            // f32 4096x64 [k3..k9]
  float* acum             = (float*)(ws + 107479040ull);            // f32 128x2048 [k4..k9]
  float* ybuf             = (float*)(ws + 108527616ull);            // f32 4096x4096 [k6..k10]
  unsigned short* hbuf    = (unsigned short*)(ws + 108527616ull);   // bf16 4096x2048 [k1..k2]
  unsigned short* gbuf    = (unsigned short*)(ws + 108527616ull);   // bf16 4096x5632 [k13..k15]
  unsigned short* WT_in   = (unsigned short*)(ws + 125304832ull);   // bf16 8704x2048 [k0..k2]
  unsigned short* h2      = (unsigned short*)(ws + 154664960ull);   // bf16 4096x2048 [k12..k13]
  float* h1               = (float*)d_out;                          // f32 4096x2048 [k11..k16]
  float* outp             = (float*)d_out;

  const int dynLDS3 = 73728;   // 3 x 24KB -> 2 blocks/CU
  const int dynLDS4 = 49152;   // 3 x 16KB -> 3 blocks/CU
  hipFuncSetAttribute((const void*)gemm3_kernel,
                      hipFuncAttributeMaxDynamicSharedMemorySize, dynLDS3);
  hipFuncSetAttribute((const void*)gemm4_kernel,
                      hipFuncAttributeMaxDynamicSharedMemorySize, dynLDS4);

  // 0. convert in_proj weight -> bf16 [8704][2048] (rows >= 8512 zeroed)
  wconv_kernel<<<dim3(136, 32), 256, 0, stream>>>(in_proj_w, WT_in, DMODEL, INP);
  // 1. h = rmsnorm(hidden) -> bf16
  rms_kernel<<<NTOK, 256, 0, stream>>>(hidden, norm1_w, hbuf, DMODEL);
  // 2. zxbcdt = h @ in_proj: cols<4096 -> zbuf, cols>=4096 -> xdt; dt cols fp32 -> dtraw
  gemm3_kernel<<<dim3(34, 32), 512, dynLDS3, stream>>>(hbuf, WT_in, nullptr, nullptr,
                                                       zbuf, xdt, DINNER, nullptr, dtraw,
                                                       NTOK, INP, DMODEL);
  // 3. dt = softplus(dtraw + bias)
  dt_kernel<<<NTOK * NH / 256, 256, 0, stream>>>(dtraw, dt_bias, dtb);
  // 4. per-chunk cumsum of dt*A
  acum_kernel<<<BATCH * NH * NCH, 64, 0, stream>>>(dtb, A_log, acum);
  // 5. conv + silu (4 l's per thread)
  conv_kernel<<<dim3(CONVD / 256, LTOT / 4, BATCH), 256, 0, stream>>>(xdt, conv_w, conv_b, xbc);
  // 6. SSD intra-chunk: Y_diag
  ssd_sy_kernel<<<dim3(NH, NCH * 2, BATCH), 256, 0, stream>>>(xbc, dtb, acum, ybuf);
  // 7. SSD per-chunk states
  ssd_states_kernel<<<dim3(NH, NCH, BATCH), 256, 0, stream>>>(xbc, dtb, acum, states);
  // 8. inter-chunk scan (in-place -> prev), j split 8x
  scan_kernel<<<dim3(BATCH * NH, 8), 256, 0, stream>>>(states, acum);
  // 9. SSD off-diagonal + D*x
  ssd3_kernel<<<dim3(NH, NCH, BATCH), 256, 0, stream>>>(xbc, states, acum, D_param, ybuf);
  // 10. gated rmsnorm: ygn = rmsnorm(y * silu(z))
  rms_gated_kernel<<<NTOK, 256, 0, stream>>>(ybuf, zbuf, mixer_w, ygn);
  // 10.5 convert out_proj weight (xbc region dead)
  wconv_kernel<<<dim3(32, 64), 256, 0, stream>>>(out_proj_w, WT_out, DINNER, DMODEL);
  // 11. h1 = hidden + ygn @ out_proj (into d_out); 512 blocks, 3/CU, single round
  gemm4_kernel<<<dim3(16, 32), 256, dynLDS4, stream>>>(ygn, WT_out, hidden, h1,
                                                       NTOK, DMODEL, DINNER);
  // 12. h2 = rmsnorm(h1) -> bf16 (h2 relocated to ybuf-region tail)
  rms_kernel<<<NTOK, 256, 0, stream>>>(h1, norm2_w, h2, DMODEL);
  // 12.5 convert gate+up weights into concatenated WT_cat [11264][2048]
  wconv_kernel<<<dim3(88, 32), 256, 0, stream>>>(gate_w, WT_cat, DMODEL, INTER_);
  wconv_kernel<<<dim3(88, 32), 256, 0, stream>>>(up_w, WT_cat + 11534336ull, DMODEL, INTER_);
  // 13. fused gate+up GEMM: N=11264, cols<5632 -> gbuf (raw g), cols>=5632 -> ubuf (raw u)
  //     1408 blocks @ 2/CU -> 2.75 rounds, 92% util (vs 2x69% separate)
  gemm3_kernel<<<dim3(44, 32), 512, dynLDS3, stream>>>(h2, WT_cat, nullptr, nullptr,
                                                       gbuf, ubuf, INTER_, nullptr, nullptr,
                                                       NTOK, 2 * INTER_, DMODEL);
  // 13.5 gbuf = silu(gbuf) * ubuf
  act_kernel<<<2048, 256, 0, stream>>>(gbuf, ubuf, NTOK * INTER_ / 8);
  // 14. convert down weight (WT_cat dead)
  wconv_kernel<<<dim3(32, 88), 256, 0, stream>>>(down_w, WT_down, INTER_, DMODEL);
  // 15. out = h1 + (g*u) @ down_w (in place on d_out); 512 blocks, 3/CU
  gemm4_kernel<<<dim3(16, 32), 256, dynLDS4, stream>>>(gbuf, WT_down, h1, outp,
                                                       NTOK, DMODEL, INTER_);
}